// Round 9
// baseline (277.270 us; speedup 1.0000x reference)
//
#include <hip/hip_runtime.h>
#include <hip/hip_bf16.h>
#include <math.h>

#define NN 10000
#define EE 160000
#define KK 128
#define GG 16
#define NE 10
#define SQ3F 1.7320508075688772f
#define INV_SQ3 0.57735026918962576f
#define INV_AVG 0.0625f
#define RMAXI 0.2f

#define WPAD 136   // 128 + 8 shorts padding
#define PLANE 16384
#define PAIR 32768
// plane-pair indices: 0 ms1_T0, 1 ms1_T1, 2 c_T0, 3 c_T1, 4 u2s_T0,
// 5..14 sk2_T0[z], 15..24 sk2_T1[z], 25 ms2_T0, 26 ms2_T1, 27 d_T1

typedef __attribute__((ext_vector_type(8))) short bf16x8;
typedef __attribute__((ext_vector_type(4))) float f32x4;

__device__ __forceinline__ void atomAddF(float* p, float v) { unsafeAtomicAdd(p, v); }

__device__ __forceinline__ float waveRed(float v) {
#pragma unroll
    for (int m = 32; m >= 1; m >>= 1) v += __shfl_xor(v, m);
    return v;
}

__device__ __forceinline__ unsigned short bfrn(float x) {
    unsigned u = __float_as_uint(x);
    return (unsigned short)((u + 0x7FFFu + ((u >> 16) & 1u)) >> 16);
}
__device__ __forceinline__ float bf2f(unsigned short b) {
    return __uint_as_float(((unsigned)b) << 16);
}
__device__ __forceinline__ short bfbits(__hip_bfloat16 h) {
    union { __hip_bfloat16 b; unsigned short u; } c; c.b = h; return (short)c.u;
}

// convert one 256-elem slice of a weight matrix into hi/lo bf16 planes [c][k]
__device__ __forceinline__ void convPlane(const float* __restrict__ src, int trans,
                                          unsigned short* __restrict__ dst, int r6) {
    const int t = threadIdx.x;
    const int elem = r6 * 256 + t;          // 0..16383
    const int c = elem >> 7, k = elem & 127;
    const float v = trans ? src[c * KK + k] : src[k * KK + c];
    const unsigned short hb = bfrn(v);
    dst[c * KK + k] = hb;
    dst[PLANE + c * KK + k] = bfrn(v - bf2f(hb));
}

// ============ dense core: 128 rows x 64 cols per block, split-bf16 MFMA ============
// 4 waves; each wave computes 2 row-frags (32 rows) x 64 cols -> each B LDS read
// feeds 6 MFMAs (was 3): halves per-output LDS traffic (the measured bottleneck).
__device__ __forceinline__ void t_stagep(const unsigned short* __restrict__ P, int h,
                                         unsigned short* WhL, unsigned short* WlL) {
    const int t = threadIdx.x;
    const bf16x8* __restrict__ Sh = (const bf16x8*)(P + (size_t)(h * 64) * KK);
    const bf16x8* __restrict__ Sl = (const bf16x8*)(P + PLANE + (size_t)(h * 64) * KK);
#pragma unroll
    for (int i = 0; i < 4; i++) {
        const int v = t + i * 256;
        const int c = v >> 4, kv = v & 15;
        *(bf16x8*)&WhL[c * WPAD + kv * 8] = Sh[c * 16 + kv];
        *(bf16x8*)&WlL[c * WPAD + kv * 8] = Sl[c * 16 + kv];
    }
}

// legacy convert-stage (used only for Wc/Wd build inside tz_geomtab, TRANS=0)
__device__ __forceinline__ void t_stage_cvt(const float* __restrict__ W, int h,
                                            unsigned short* WhL, unsigned short* WlL) {
    const int t = threadIdx.x;
    for (int i = t; i < 64 * KK; i += 256) {
        const int k = i >> 6, c = i & 63;
        const float v = W[k * KK + (h * 64 + c)];
        const unsigned short hb = bfrn(v);
        WhL[c * WPAD + k] = hb;
        WlL[c * WPAD + k] = bfrn(v - bf2f(hb));
    }
}

template <int ACCUM, int GATHER>
__device__ __forceinline__ void t_compute(const float* __restrict__ in, float* __restrict__ out,
                                          int rows, float alpha, int bid_row, int h,
                                          const int* __restrict__ rowlist,
                                          const unsigned short* WhL, const unsigned short* WlL) {
    const int t = threadIdx.x;
    const int w = t >> 6;            // wave 0..3
    const int l = t & 63;
    const int lr = l & 15;           // A row within frag / D col within 16-col tile
    const int ls = l >> 4;           // k-slice (A) / D row group
    const int rbase = bid_row * 128 + w * 32;
    const float* Ap[2];
#pragma unroll
    for (int m = 0; m < 2; m++) {
        int idx = rbase + m * 16 + lr;
        if (idx > rows - 1) idx = rows - 1;
        const int ar = GATHER ? rowlist[idx] : idx;
        Ap[m] = in + (size_t)ar * KK + ls * 8;
    }
    int rowv[2][4];
#pragma unroll
    for (int m = 0; m < 2; m++)
#pragma unroll
        for (int r = 0; r < 4; r++) {
            int idx = rbase + m * 16 + ls * 4 + r;
            if (idx > rows - 1) idx = rows - 1;
            rowv[m][r] = GATHER ? rowlist[idx] : idx;
        }
    f32x4 acc[2][4];
#pragma unroll
    for (int m = 0; m < 2; m++)
#pragma unroll
        for (int ct = 0; ct < 4; ct++) { acc[m][ct][0] = 0.f; acc[m][ct][1] = 0.f; acc[m][ct][2] = 0.f; acc[m][ct][3] = 0.f; }

#pragma unroll
    for (int kc = 0; kc < 4; kc++) {               // K chunks of 32
        bf16x8 ah[2], al[2];
#pragma unroll
        for (int m = 0; m < 2; m++) {
            const float4 a0 = *(const float4*)(Ap[m] + kc * 32);
            const float4 a1 = *(const float4*)(Ap[m] + kc * 32 + 4);
            const float av[8] = {a0.x, a0.y, a0.z, a0.w, a1.x, a1.y, a1.z, a1.w};
#pragma unroll
            for (int j = 0; j < 8; j++) {
                const float v = av[j];
                const __hip_bfloat16 hb = __float2bfloat16(v);
                const float hf = __bfloat162float(hb);
                ah[m][j] = bfbits(hb);
                al[m][j] = bfbits(__float2bfloat16(v - hf));
            }
        }
#pragma unroll
        for (int ct = 0; ct < 4; ct++) {
            const int col = ct * 16 + lr;
            const bf16x8 bh = *(const bf16x8*)&WhL[col * WPAD + kc * 32 + ls * 8];
            const bf16x8 bl = *(const bf16x8*)&WlL[col * WPAD + kc * 32 + ls * 8];
            acc[0][ct] = __builtin_amdgcn_mfma_f32_16x16x32_bf16(ah[0], bh, acc[0][ct], 0, 0, 0);
            acc[0][ct] = __builtin_amdgcn_mfma_f32_16x16x32_bf16(al[0], bh, acc[0][ct], 0, 0, 0);
            acc[0][ct] = __builtin_amdgcn_mfma_f32_16x16x32_bf16(ah[0], bl, acc[0][ct], 0, 0, 0);
            acc[1][ct] = __builtin_amdgcn_mfma_f32_16x16x32_bf16(ah[1], bh, acc[1][ct], 0, 0, 0);
            acc[1][ct] = __builtin_amdgcn_mfma_f32_16x16x32_bf16(al[1], bh, acc[1][ct], 0, 0, 0);
            acc[1][ct] = __builtin_amdgcn_mfma_f32_16x16x32_bf16(ah[1], bl, acc[1][ct], 0, 0, 0);
        }
    }

#pragma unroll
    for (int m = 0; m < 2; m++)
#pragma unroll
        for (int r = 0; r < 4; r++) {
            const int gr = rbase + m * 16 + ls * 4 + r;
            if (gr < rows) {
                float* orow = out + (size_t)rowv[m][r] * KK + h * 64;
#pragma unroll
                for (int ct = 0; ct < 4; ct++) {
                    float v = acc[m][ct][r] * alpha;
                    if (ACCUM) v += orow[ct * 16 + lr];
                    orow[ct * 16 + lr] = v;
                }
            }
        }
}

// ---------------- zero-init: out + int counters + weight-plane conversion ----------------
__global__ __launch_bounds__(256) void tz_zero(float* __restrict__ out, int out_size,
                                               int* __restrict__ ints, int icount, int zb, int zi,
                                               const float* __restrict__ Wms1,
                                               const float* __restrict__ Wu2s,
                                               const float* __restrict__ Wsk2,
                                               const float* __restrict__ Wms2,
                                               unsigned short* __restrict__ wp) {
    const int t = threadIdx.x;
    if ((int)blockIdx.x < zb) {
        const int i = blockIdx.x * 256 + t;
        if (i < out_size) out[i] = 0.f;
    } else if ((int)blockIdx.x < zb + zi) {
        const int i = (blockIdx.x - zb) * 256 + t;
        if (i < icount) ints[i] = 0;
    } else {
        const int bb = blockIdx.x - (zb + zi);
        const int pr = bb >> 6, r6 = bb & 63;
        const float* src; int tr, pi;
        if (pr == 0)       { src = Wms1; tr = 0; pi = 0; }
        else if (pr == 1)  { src = Wms1; tr = 1; pi = 1; }
        else if (pr == 2)  { src = Wu2s; tr = 0; pi = 4; }
        else if (pr < 13)  { src = Wsk2 + (size_t)(pr - 3) * PLANE;  tr = 0; pi = 5 + (pr - 3); }
        else if (pr < 23)  { src = Wsk2 + (size_t)(pr - 13) * PLANE; tr = 1; pi = 15 + (pr - 13); }
        else if (pr == 23) { src = Wms2; tr = 0; pi = 25; }
        else               { src = Wms2; tr = 1; pi = 26; }
        convPlane(src, tr, wp + (size_t)pi * PAIR, r6);
    }
}

// ---------------- merged: geom (0..624) + zcount (625..664) + tables (665..674) + Wc (675..676) + Wd (677..678) ----------------
__global__ __launch_bounds__(256) void tz_geomtab(const float* __restrict__ pos, const float* __restrict__ shifts,
                            const int* __restrict__ ei,
                            float* __restrict__ ef, float* __restrict__ defdr,
                            float* __restrict__ Y1, float* __restrict__ rr,
                            int2* __restrict__ cei, int* __restrict__ nact,
                            int* __restrict__ deg_r, int* __restrict__ deg_s,
                            const int* __restrict__ z, int* __restrict__ zcnt,
                            const float* __restrict__ We, const float* __restrict__ Wup1,
                            const float* __restrict__ Wsk1,
                            float* __restrict__ E1, float* __restrict__ T1,
                            const float* __restrict__ Wmv1, const float* __restrict__ Wu2v,
                            float* __restrict__ Wc,
                            const float* __restrict__ Wms1, const float* __restrict__ Wu2s,
                            float* __restrict__ Wd) {
    __shared__ unsigned short WhL[64 * WPAD];
    __shared__ unsigned short WlL[64 * WPAD];
    const int t = threadIdx.x;
    if ((int)blockIdx.x < 625) {
        int* lcnt = (int*)WhL;
        int* lbase = ((int*)WhL) + 1;
        if (t == 0) *lcnt = 0;
        __syncthreads();
        const int e = blockIdx.x * 256 + t;
        const int sn = ei[e];
        const int rv = ei[EE + e];
        const float vx = pos[rv*3+0] - pos[sn*3+0] + shifts[e*3+0];
        const float vy = pos[rv*3+1] - pos[sn*3+1] + shifts[e*3+1];
        const float vz = pos[rv*3+2] - pos[sn*3+2] + shifts[e*3+2];
        const float r = sqrtf(vx*vx + vy*vy + vz*vz + 1e-12f);
        const float x = r * RMAXI;
        const int active = (x < 1.0f) ? 1 : 0;
        int pos_l = 0;
        if (active) pos_l = atomicAdd(lcnt, 1);
        __syncthreads();
        if (t == 0 && *lcnt > 0) *lbase = atomicAdd(nact, *lcnt);
        __syncthreads();
        if (!active) return;
        const int idx = *lbase + pos_l;
        cei[idx] = make_int2(sn, rv);
        atomicAdd(&deg_s[sn], 1);
        atomicAdd(&deg_r[rv], 1);
        const float ir = 1.0f / r;
        rr[idx] = r;
        Y1[idx*3+0] = SQ3F*vx*ir;
        Y1[idx*3+1] = SQ3F*vy*ir;
        Y1[idx*3+2] = SQ3F*vz*ir;
        const float x2 = x*x, x4 = x2*x2, x5 = x4*x, x6 = x5*x, x7 = x6*x;
        const float fc  = 1.0f - 21.0f*x5 + 35.0f*x6 - 15.0f*x7;
        const float dfc = (-105.0f*x4 + 210.0f*x5 - 105.0f*x6) * RMAXI;
        const float C = 0.63245553203367587f;
        float4 efa, efb4, da, db;
        float* efp = (float*)&efa;
        float* dp  = (float*)&da;
#pragma unroll
        for (int b = 0; b < 8; b++) {
            const float kb = (float)(b + 1) * 0.62831853071795865f;
            float sb, cb;
            sincosf(kb * r, &sb, &cb);
            const float bess  = C * sb * ir;
            const float dbess = C * ir * (kb * cb - sb * ir);
            if (b == 4) { efp = (float*)&efb4; dp = (float*)&db; }
            efp[b & 3] = bess * fc;
            dp[b & 3]  = dbess * fc + bess * dfc;
        }
        ((float4*)ef)[idx*2]    = efa;
        ((float4*)ef)[idx*2+1]  = efb4;
        ((float4*)defdr)[idx*2]   = da;
        ((float4*)defdr)[idx*2+1] = db;
    } else if ((int)blockIdx.x < 665) {
        int* h = (int*)WhL;
        if (t < NE) h[t] = 0;
        __syncthreads();
        const int n = (blockIdx.x - 625) * 256 + t;
        if (n < NN) atomicAdd(&h[z[n]], 1);
        __syncthreads();
        if (t < NE && h[t] > 0) atomicAdd(&zcnt[t], h[t]);
    } else if ((int)blockIdx.x < 675) {
        const int zz = blockIdx.x - 665;
        if (t < KK) {
            float a = 0.f, bv = 0.f;
            for (int c = 0; c < KK; c++) {
                const float w = We[zz*KK + c];
                a  += w * Wup1[c*KK + t];
                bv += w * Wsk1[(size_t)(zz*KK + c)*KK + t];
            }
            E1[zz*KK + t] = a;
            T1[zz*KK + t] = bv;
        }
    } else if ((int)blockIdx.x < 677) {
        const int hh = blockIdx.x - 675;     // 0..1: Wc = Wmv1 @ Wu2v
        t_stage_cvt(Wu2v, hh, WhL, WlL);
        __syncthreads();
        t_compute<0, 0>(Wmv1, Wc, KK, 1.f, 0, hh, nullptr, WhL, WlL);
    } else {
        const int hh = blockIdx.x - 677;     // 0..1: Wd = Wms1 @ Wu2s
        t_stage_cvt(Wu2s, hh, WhL, WlL);
        __syncthreads();
        t_compute<0, 0>(Wms1, Wd, KK, 1.f, 0, hh, nullptr, WhL, WlL);
    }
}

// ---------------- packed scan via wave shuffles (deg_r lo32, deg_s hi32), 2 barriers ----------------
__global__ __launch_bounds__(1024) void tz_scan(const int* __restrict__ deg_r, const int* __restrict__ deg_s,
                                               const int* __restrict__ zcnt,
                                               int* __restrict__ row_r, int* __restrict__ row_s,
                                               int* __restrict__ zrow) {
    __shared__ unsigned long long wsum[16];
    __shared__ unsigned long long wscan[16];
    const int t = threadIdx.x;
    const int lane = t & 63;
    const int wid = t >> 6;
    if (t == 0) {
        int s = 0;
        for (int i = 0; i < NE; i++) { zrow[i] = s; s += zcnt[i]; }
        zrow[NE] = s;
    }
    const int base = t * 10;
    unsigned long long loc[10];
    unsigned long long s = 0;
#pragma unroll
    for (int k = 0; k < 10; k++) {
        loc[k] = s;
        if (base + k < NN)
            s += ((unsigned long long)(unsigned)deg_s[base + k] << 32) | (unsigned)deg_r[base + k];
    }
    unsigned long long x = s;
#pragma unroll
    for (int off = 1; off < 64; off <<= 1) {
        const unsigned long long y = __shfl_up((long long)x, off);
        if (lane >= off) x += y;
    }
    if (lane == 63) wsum[wid] = x;
    __syncthreads();
    if (wid == 0 && lane < 16) {
        unsigned long long v = wsum[lane];
#pragma unroll
        for (int off = 1; off < 16; off <<= 1) {
            const unsigned long long y = __shfl_up((long long)v, off);
            if (lane >= off) v += y;
        }
        wscan[lane] = v;
    }
    __syncthreads();
    const unsigned long long woff = (wid > 0) ? wscan[wid - 1] : 0ull;
    const unsigned long long bex = woff + x - s;   // exclusive prefix for this thread
#pragma unroll
    for (int k = 0; k < 10; k++)
        if (base + k < NN) {
            const unsigned long long p = bex + loc[k];
            row_r[base + k] = (int)(p & 0xffffffffu);
            row_s[base + k] = (int)(p >> 32);
        }
    if (t == 1023) {
        const unsigned long long p = wscan[15];
        row_r[NN] = (int)(p & 0xffffffffu);
        row_s[NN] = (int)(p >> 32);
    }
}

// ---------------- merged: CSR fill (0..624) + zfill (625..664) + zinit (665..5664) + Wc/Wd planes ----------------
__global__ __launch_bounds__(256) void tz_fill3(const int2* __restrict__ cei, const int* __restrict__ nact,
                       const int* __restrict__ row_r, const int* __restrict__ row_s,
                       int* __restrict__ cur_r, int* __restrict__ cur_s,
                       int2* __restrict__ list_r, int2* __restrict__ list_s,
                       const int* __restrict__ z, int* __restrict__ zcur,
                       const int* __restrict__ zrow, int* __restrict__ zlist,
                       const float* __restrict__ E1, const float* __restrict__ T1,
                       float* __restrict__ su1, float* __restrict__ s1,
                       const float* __restrict__ Wc, const float* __restrict__ Wd,
                       unsigned short* __restrict__ wp) {
    const int t = threadIdx.x;
    if ((int)blockIdx.x < 625) {
        const int i = blockIdx.x * 256 + t;
        if (i >= *nact) return;
        const int2 p = cei[i];
        const int pr = atomicAdd(&cur_r[p.y], 1);
        list_r[row_r[p.y] + pr] = make_int2(i, p.x);
        const int ps = atomicAdd(&cur_s[p.x], 1);
        list_s[row_s[p.x] + ps] = make_int2(i, p.y);
    } else if ((int)blockIdx.x < 665) {
        __shared__ int cnt[NE];
        __shared__ int base[NE];
        if (t < NE) cnt[t] = 0;
        __syncthreads();
        const int n = (blockIdx.x - 625) * 256 + t;
        int pos = -1, zz = 0;
        if (n < NN) { zz = z[n]; pos = atomicAdd(&cnt[zz], 1); }
        __syncthreads();
        if (t < NE && cnt[t] > 0) base[t] = atomicAdd(&zcur[t], cnt[t]);
        __syncthreads();
        if (n < NN) zlist[zrow[zz] + base[zz] + pos] = n;
    } else if ((int)blockIdx.x < 5665) {
        const int i = (blockIdx.x - 665) * 256 + t;
        if (i >= NN * KK) return;
        const int base = z[i >> 7] * KK + (i & 127);
        su1[i] = E1[base];
        s1[i]  = T1[base];
    } else {
        const int bb = blockIdx.x - 5665;
        const int pr = bb >> 6, r6 = bb & 63;
        if (pr == 0)      convPlane(Wc, 0, wp + (size_t)2 * PAIR, r6);
        else if (pr == 1) convPlane(Wc, 1, wp + (size_t)3 * PAIR, r6);
        else              convPlane(Wd, 1, wp + (size_t)27 * PAIR, r6);
    }
}

// ---- single dense op ----
template <int ACCUM>
__global__ __launch_bounds__(256) void tz_one(const float* __restrict__ in, const unsigned short* __restrict__ P,
                                              float* __restrict__ out, int rows, float alpha) {
    __shared__ unsigned short WhL[64 * WPAD];
    __shared__ unsigned short WlL[64 * WPAD];
    const int h = blockIdx.x & 1;
    t_stagep(P, h, WhL, WlL);
    __syncthreads();
    t_compute<ACCUM, 0>(in, out, rows, alpha, blockIdx.x >> 1, h, nullptr, WhL, WlL);
}

// ---- two dense ops, one dispatch ----
template <int AA, int AB>
__global__ __launch_bounds__(256) void tz_two(
        const float* __restrict__ inA, const unsigned short* __restrict__ PA, float* __restrict__ outA,
        int rowsA, float alphaA,
        const float* __restrict__ inB, const unsigned short* __restrict__ PB, float* __restrict__ outB,
        int rowsB, float alphaB, int blocksA) {
    __shared__ unsigned short WhL[64 * WPAD];
    __shared__ unsigned short WlL[64 * WPAD];
    if ((int)blockIdx.x < blocksA) {
        const int h = blockIdx.x & 1;
        t_stagep(PA, h, WhL, WlL);
        __syncthreads();
        t_compute<AA, 0>(inA, outA, rowsA, alphaA, blockIdx.x >> 1, h, nullptr, WhL, WlL);
    } else {
        const int b = blockIdx.x - blocksA;
        const int h = b & 1;
        t_stagep(PB, h, WhL, WlL);
        __syncthreads();
        t_compute<AB, 0>(inB, outB, rowsB, alphaB, b >> 1, h, nullptr, WhL, WlL);
    }
}

// ---- three dense ops, one dispatch ----
template <int AA, int AB, int AC>
__global__ __launch_bounds__(256) void tz_three(
        const float* __restrict__ inA, const unsigned short* __restrict__ PA, float* __restrict__ outA,
        int rowsA, float alphaA,
        const float* __restrict__ inB, const unsigned short* __restrict__ PB, float* __restrict__ outB,
        int rowsB, float alphaB,
        const float* __restrict__ inC, const unsigned short* __restrict__ PC, float* __restrict__ outC,
        int rowsC, float alphaC, int blocksA, int blocksAB) {
    __shared__ unsigned short WhL[64 * WPAD];
    __shared__ unsigned short WlL[64 * WPAD];
    if ((int)blockIdx.x < blocksA) {
        const int h = blockIdx.x & 1;
        t_stagep(PA, h, WhL, WlL);
        __syncthreads();
        t_compute<AA, 0>(inA, outA, rowsA, alphaA, blockIdx.x >> 1, h, nullptr, WhL, WlL);
    } else if ((int)blockIdx.x < blocksAB) {
        const int b = blockIdx.x - blocksA;
        const int h = b & 1;
        t_stagep(PB, h, WhL, WlL);
        __syncthreads();
        t_compute<AB, 0>(inB, outB, rowsB, alphaB, b >> 1, h, nullptr, WhL, WlL);
    } else {
        const int b = blockIdx.x - blocksAB;
        const int h = b & 1;
        t_stagep(PC, h, WhL, WlL);
        __syncthreads();
        t_compute<AC, 0>(inC, outC, rowsC, alphaC, b >> 1, h, nullptr, WhL, WlL);
    }
}

// ---- dense op + per-z skip buckets, one dispatch ----
template <int AA, int AS>
__global__ __launch_bounds__(256) void tz_mix(
        const float* __restrict__ inA, const unsigned short* __restrict__ PA, float* __restrict__ outA,
        int rowsA, float alphaA,
        const float* __restrict__ inS, const unsigned short* __restrict__ PSbase, float* __restrict__ outS,
        const int* __restrict__ zrow, const int* __restrict__ zlist, int blocksA) {
    __shared__ unsigned short WhL[64 * WPAD];
    __shared__ unsigned short WlL[64 * WPAD];
    if ((int)blockIdx.x < blocksA) {
        const int h = blockIdx.x & 1;
        t_stagep(PA, h, WhL, WlL);
        __syncthreads();
        t_compute<AA, 0>(inA, outA, rowsA, alphaA, blockIdx.x >> 1, h, nullptr, WhL, WlL);
    } else {
        const int sbid = blockIdx.x - blocksA;
        const int zz = sbid % NE;
        const int q = sbid / NE;            // 0..15
        const int h = q & 1;
        const int ch0 = q >> 1;             // 0..7
        const int beg = zrow[zz];
        const int cnt = zrow[zz + 1] - beg;
        if (ch0 * 128 >= cnt) return;
        t_stagep(PSbase + (size_t)zz * PAIR, h, WhL, WlL);
        __syncthreads();
        for (int ch = ch0; ch * 128 < cnt; ch += 8)
            t_compute<AS, 1>(inS, outS, cnt, 1.f, ch, h, zlist + beg, WhL, WlL);
    }
}

// ---- backward bundle: dense g_A2 + skip bwd accum + energy (last 32) ----
__global__ __launch_bounds__(256) void tz_bwdmix(
        const float* __restrict__ g_s2, const unsigned short* __restrict__ Pms2t, float* __restrict__ gA2,
        const unsigned short* __restrict__ Psk2t, float* __restrict__ g_s1,
        const int* __restrict__ zrow, const int* __restrict__ zlist,
        const int* __restrict__ z, const int* __restrict__ batch, const float* __restrict__ ae,
        const float* __restrict__ e1n, const float* __restrict__ e2n, float* __restrict__ out,
        int blocksA, int blocksAB) {
    __shared__ unsigned short WhL[64 * WPAD];
    __shared__ unsigned short WlL[64 * WPAD];
    const int t = threadIdx.x;
    if ((int)blockIdx.x < blocksA) {
        const int h = blockIdx.x & 1;
        t_stagep(Pms2t, h, WhL, WlL);
        __syncthreads();
        t_compute<0, 0>(g_s2, gA2, NN, INV_AVG, blockIdx.x >> 1, h, nullptr, WhL, WlL);
    } else if ((int)blockIdx.x < blocksAB) {
        const int sbid = blockIdx.x - blocksA;
        const int zz = sbid % NE;
        const int q = sbid / NE;            // 0..15
        const int h = q & 1;
        const int ch0 = q >> 1;             // 0..7
        const int beg = zrow[zz];
        const int cnt = zrow[zz + 1] - beg;
        if (ch0 * 128 >= cnt) return;
        t_stagep(Psk2t + (size_t)zz * PAIR, h, WhL, WlL);
        __syncthreads();
        for (int ch = ch0; ch * 128 < cnt; ch += 8)
            t_compute<1, 1>(g_s2, g_s1, cnt, 1.f, ch, h, zlist + beg, WhL, WlL);
    } else {
        float* bins = (float*)WhL;
        for (int i = t; i < GG * 4; i += 256) bins[i] = 0.f;
        __syncthreads();
        const int idx = (blockIdx.x - blocksAB) * 256 + t;
        const int stride = 32 * 256;
        for (int n = idx; n < NN; n += stride) {
            const int b = batch[n];
            const float v0 = ae[z[n]];
            const float v1 = e1n[n];
            const float v2 = e2n[n];
            atomicAdd(&bins[b*4+0], v0 + v1 + v2);
            atomicAdd(&bins[b*4+1], v0);
            atomicAdd(&bins[b*4+2], v1);
            atomicAdd(&bins[b*4+3], v2);
        }
        __syncthreads();
        for (int i = t; i < GG * 4; i += 256) {
            const float v = bins[i];
            if (v != 0.f) {
                const int b = i >> 2;
                const int k = i & 3;
                float* dst = (k == 0) ? &out[b] : &out[GG + b*3 + (k - 1)];
                atomAddF(dst, v);
            }
        }
    }
}

// ---------------- edge pass 1 (rcv-centric gather, 16 nodes/block) ----------------
__global__ __launch_bounds__(256) void tz_edge1(const float* __restrict__ ef, const float* __restrict__ Y1,
                                                 const float* __restrict__ R1, const float* __restrict__ su1,
                                                 const int* __restrict__ row_r, const int2* __restrict__ list_r,
                                                 float* __restrict__ A0, float* __restrict__ A1) {
    __shared__ float RL[2048];
    for (int i = threadIdx.x; i < 2048; i += 256) RL[i] = R1[i];
    __syncthreads();
    const int lane = threadIdx.x & 63;
    const int sub = threadIdx.x >> 6;
    const int c0 = lane;
    const int c1 = lane + 64;
    for (int cc = 0; cc < 4; cc++) {
        const int n = blockIdx.x * 16 + cc * 4 + sub;
        if (n >= NN) break;
        float a00 = 0.f, a01 = 0.f;
        float ax0 = 0.f, ax1 = 0.f, ay0 = 0.f, ay1 = 0.f, az0 = 0.f, az1 = 0.f;
        const int beg = row_r[n];
        const int end = row_r[n + 1];
        for (int i = beg; i < end; i++) {
            const int2 p = list_r[i];
            const int e = p.x;
            const int sn = p.y;
            const float4 efa = ((const float4*)ef)[e*2];
            const float4 efb4 = ((const float4*)ef)[e*2+1];
            const float y0 = Y1[e*3+0], y1 = Y1[e*3+1], y2 = Y1[e*3+2];
            float wa0 = 0.f, wa1 = 0.f, wb0 = 0.f, wb1 = 0.f;
            const float* eb = (const float*)&efa;
#pragma unroll
            for (int b = 0; b < 8; b++) {
                if (b == 4) eb = (const float*)&efb4;
                const float v = eb[b & 3];
                wa0 += v * RL[b*256 + c0];
                wb0 += v * RL[b*256 + 128 + c0];
                wa1 += v * RL[b*256 + c1];
                wb1 += v * RL[b*256 + 128 + c1];
            }
            const float sj0 = su1[sn*KK + c0];
            const float sj1 = su1[sn*KK + c1];
            a00 += wa0 * sj0;
            a01 += wa1 * sj1;
            const float mb0 = wb0 * sj0;
            const float mb1 = wb1 * sj1;
            ax0 += mb0*y0; ax1 += mb1*y0;
            ay0 += mb0*y1; ay1 += mb1*y1;
            az0 += mb0*y2; az1 += mb1*y2;
        }
        A0[(size_t)n*KK + c0] = a00;
        A0[(size_t)n*KK + c1] = a01;
        float* A1r = A1 + (size_t)n * 384;
        A1r[c0] = ax0;        A1r[c1] = ax1;
        A1r[128 + c0] = ay0;  A1r[128 + c1] = ay1;
        A1r[256 + c0] = az0;  A1r[256 + c1] = az1;
    }
}

// ---------------- edge pass 2 (rcv-centric gather, 16 nodes/block) ----------------
__global__ __launch_bounds__(256) void tz_edge2(const float* __restrict__ ef, const float* __restrict__ Y1,
                                                 const float* __restrict__ R2, const float* __restrict__ s1u2,
                                                 const float* __restrict__ vup,
                                                 const int* __restrict__ row_r, const int2* __restrict__ list_r,
                                                 float* __restrict__ A2) {
    __shared__ float RL[2048];
    for (int i = threadIdx.x; i < 2048; i += 256) RL[i] = R2[(i >> 8) * 512 + (i & 255)];
    __syncthreads();
    const int lane = threadIdx.x & 63;
    const int sub = threadIdx.x >> 6;
    const int c0 = lane;
    const int c1 = lane + 64;
    for (int cc = 0; cc < 4; cc++) {
        const int n = blockIdx.x * 16 + cc * 4 + sub;
        if (n >= NN) break;
        float a0 = 0.f, a1 = 0.f;
        const int beg = row_r[n];
        const int end = row_r[n + 1];
        for (int i = beg; i < end; i++) {
            const int2 p = list_r[i];
            const int e = p.x;
            const int sn = p.y;
            const float4 efa = ((const float4*)ef)[e*2];
            const float4 efb4 = ((const float4*)ef)[e*2+1];
            const float y0 = Y1[e*3+0], y1 = Y1[e*3+1], y2 = Y1[e*3+2];
            float w00_0 = 0.f, w00_1 = 0.f, w110_0 = 0.f, w110_1 = 0.f;
            const float* eb = (const float*)&efa;
#pragma unroll
            for (int b = 0; b < 8; b++) {
                if (b == 4) eb = (const float*)&efb4;
                const float v = eb[b & 3];
                w00_0  += v * RL[b*256 + c0];
                w110_0 += v * RL[b*256 + 128 + c0];
                w00_1  += v * RL[b*256 + c1];
                w110_1 += v * RL[b*256 + 128 + c1];
            }
            const float sj0 = s1u2[sn*KK + c0];
            const float sj1 = s1u2[sn*KK + c1];
            const float* vu = vup + (size_t)sn * 384;
            const float tt0 = (vu[c0]*y0 + vu[128 + c0]*y1 + vu[256 + c0]*y2) * INV_SQ3;
            const float tt1 = (vu[c1]*y0 + vu[128 + c1]*y1 + vu[256 + c1]*y2) * INV_SQ3;
            a0 += w00_0 * sj0 + w110_0 * tt0;
            a1 += w00_1 * sj1 + w110_1 * tt1;
        }
        A2[(size_t)n*KK + c0] = a0;
        A2[(size_t)n*KK + c1] = a1;
    }
}

// ---------------- MLP energy head + e1 + backward seed (8 nodes/block, W staged once) ----------------
__global__ __launch_bounds__(256) void tz_mlp(const float* __restrict__ s2, const float* __restrict__ W_mlp,
                                             const float* __restrict__ w_out, const float* __restrict__ w_r1,
                                             const float* __restrict__ s1,
                                             float* __restrict__ g_s2, float* __restrict__ g_s1,
                                             float* __restrict__ e1n, float* __restrict__ e2n) {
    __shared__ float WmL[KK * 17];
    __shared__ float s2L[2][KK];
    __shared__ float part[256];
    __shared__ float ghL[2][16];
    __shared__ float eL[2][16];
    __shared__ float pw[4];
    const int t = threadIdx.x;
    const int grp = t >> 7;
    const int tl = t & 127;
    for (int i = t; i < KK * 16; i += 256) WmL[(i >> 4) * 17 + (i & 15)] = W_mlp[i];
    const float wr = w_r1[tl];
    const float wo = (tl < 16) ? w_out[tl] : 0.f;
    __syncthreads();
    for (int it = 0; it < 4; ++it) {
        const int n = blockIdx.x * 8 + it * 2 + grp;
        s2L[grp][tl] = s2[(size_t)n * KK + tl];
        float p = s1[(size_t)n * KK + tl] * wr;
        p = waveRed(p);
        if ((t & 63) == 0) pw[t >> 6] = p;
        __syncthreads();
        {
            const int j = tl & 15;
            const int seg = tl >> 4;
            float pr = 0.f;
#pragma unroll
            for (int c = 0; c < 16; c++) pr += s2L[grp][seg*16 + c] * WmL[(seg*16 + c) * 17 + j];
            part[t] = pr;
        }
        __syncthreads();
        if (tl < 16) {
            float hh = 0.f;
#pragma unroll
            for (int s = 0; s < 8; s++) hh += part[grp*128 + s*16 + tl];
            const float sg = 1.f / (1.f + expf(-hh));
            eL[grp][tl]  = hh * sg * wo;
            ghL[grp][tl] = wo * sg * (1.f + hh * (1.f - sg));
        }
        __syncthreads();
        if (tl == 0) {
            float e = 0.f;
#pragma unroll
            for (int j = 0; j < 16; j++) e += eL[grp][j];
            e2n[n] = e;
            e1n[n] = pw[grp*2] + pw[grp*2+1];
        }
        float g = 0.f;
#pragma unroll
        for (int j = 0; j < 16; j++) g += ghL[grp][j] * WmL[tl * 17 + j];
        g_s2[(size_t)n * KK + tl] = g;
        g_s1[(size_t)n * KK + tl] = wr;
        __syncthreads();
    }
}

// ---------------- merged backward layer2: per-edge (0..624) + node sums (625.., 16 nodes/block) ----------------
__global__ __launch_bounds__(256) void tz_bwdA(const float* __restrict__ ef8, const float* __restrict__ Y1,
                                                const int2* __restrict__ cei, const int* __restrict__ nact,
                                                const float* __restrict__ R2,
                                                const float* __restrict__ gA2, const float* __restrict__ s1u2,
                                                const float* __restrict__ vup,
                                                const int2* __restrict__ list_s, const int* __restrict__ row_s,
                                                float* __restrict__ gefA, float* __restrict__ gyA,
                                                float* __restrict__ Gsj2, float* __restrict__ Gvj) {
    __shared__ float RL[2048];
    const int t = threadIdx.x;
    if ((int)blockIdx.x < 625) {
        const int i = blockIdx.x * 256 + t;
        if (i >= *nact) return;
        const int2 p = list_s[i];
        const int e = p.x;
        const int rv = p.y;
        const int sn = cei[e].x;
        const float y0 = Y1[e*3+0], y1 = Y1[e*3+1], y2 = Y1[e*3+2];
        const float4 efa = ((const float4*)ef8)[e*2];
        const float4 efb = ((const float4*)ef8)[e*2+1];
        const float efv[8] = {efa.x, efa.y, efa.z, efa.w, efb.x, efb.y, efb.z, efb.w};
        float acc[8] = {0.f,0.f,0.f,0.f,0.f,0.f,0.f,0.f};
        float g0 = 0.f, g1 = 0.f, g2 = 0.f;
        const float4* gaR = (const float4*)(gA2 + (size_t)rv * KK);
        const float4* sjR = (const float4*)(s1u2 + (size_t)sn * KK);
        const float4* vxR = (const float4*)(vup + (size_t)sn * 384);
        const float4* vyR = vxR + 32;
        const float4* vzR = vxR + 64;
        for (int cc = 0; cc < 32; cc++) {
            const float4 ga = gaR[cc];
            const float4 sj = sjR[cc];
            const float4 vx = vxR[cc];
            const float4 vy = vyR[cc];
            const float4 vz = vzR[cc];
#pragma unroll
            for (int k = 0; k < 4; k++) {
                const float gaE = ((const float*)&ga)[k];
                const float sjE = ((const float*)&sj)[k];
                const float vxE = ((const float*)&vx)[k];
                const float vyE = ((const float*)&vy)[k];
                const float vzE = ((const float*)&vz)[k];
                const float tt = (vxE*y0 + vyE*y1 + vzE*y2) * INV_SQ3;
                const float gw00 = gaE * sjE;
                const float gw110 = gaE * tt;
                float w110 = 0.f;
                const int c = cc*4 + k;
#pragma unroll
                for (int b = 0; b < 8; b++) {
                    const float r2a = R2[b*512 + c];
                    const float r2b = R2[b*512 + 128 + c];
                    acc[b] += gw00 * r2a + gw110 * r2b;
                    w110 += efv[b] * r2b;
                }
                const float gt = gaE * w110;
                g0 += gt * vxE;
                g1 += gt * vyE;
                g2 += gt * vzE;
            }
        }
        ((float4*)gefA)[e*2]   = make_float4(acc[0], acc[1], acc[2], acc[3]);
        ((float4*)gefA)[e*2+1] = make_float4(acc[4], acc[5], acc[6], acc[7]);
        gyA[e*3+0] = g0 * INV_SQ3;
        gyA[e*3+1] = g1 * INV_SQ3;
        gyA[e*3+2] = g2 * INV_SQ3;
    } else {
        for (int i = t; i < 2048; i += 256) RL[i] = R2[(i >> 8) * 512 + (i & 255)];
        __syncthreads();
        const int lane = t & 63;
        const int sub = t >> 6;
        const int c0 = lane;
        const int c1 = lane + 64;
        for (int cc2 = 0; cc2 < 4; cc2++) {
            const int sn = (blockIdx.x - 625) * 16 + cc2 * 4 + sub;
            if (sn >= NN) break;
            float gs0 = 0.f, gs1 = 0.f;
            float gv00 = 0.f, gv01 = 0.f, gv10 = 0.f, gv11 = 0.f, gv20 = 0.f, gv21 = 0.f;
            const int beg = row_s[sn];
            const int end = row_s[sn + 1];
            for (int i = beg; i < end; i++) {
                const int2 p = list_s[i];
                const int e = p.x;
                const int rv = p.y;
                const float4 efa = ((const float4*)ef8)[e*2];
                const float4 efb4 = ((const float4*)ef8)[e*2+1];
                const float y0 = Y1[e*3+0], y1 = Y1[e*3+1], y2 = Y1[e*3+2];
                float w00_0 = 0.f, w00_1 = 0.f, w110_0 = 0.f, w110_1 = 0.f;
                const float* eb = (const float*)&efa;
#pragma unroll
                for (int b = 0; b < 8; b++) {
                    if (b == 4) eb = (const float*)&efb4;
                    const float v = eb[b & 3];
                    w00_0  += v * RL[b*256 + c0];
                    w110_0 += v * RL[b*256 + 128 + c0];
                    w00_1  += v * RL[b*256 + c1];
                    w110_1 += v * RL[b*256 + 128 + c1];
                }
                const float ga0 = gA2[(size_t)rv*KK + c0];
                const float ga1 = gA2[(size_t)rv*KK + c1];
                gs0 += ga0 * w00_0;
                gs1 += ga1 * w00_1;
                const float gts0 = ga0 * w110_0 * INV_SQ3;
                const float gts1 = ga1 * w110_1 * INV_SQ3;
                gv00 += gts0*y0; gv01 += gts1*y0;
                gv10 += gts0*y1; gv11 += gts1*y1;
                gv20 += gts0*y2; gv21 += gts1*y2;
            }
            Gsj2[(size_t)sn*KK + c0] = gs0;
            Gsj2[(size_t)sn*KK + c1] = gs1;
            float* Gv = Gvj + (size_t)sn * 384;
            Gv[c0] = gv00;        Gv[c1] = gv01;
            Gv[128 + c0] = gv10;  Gv[128 + c1] = gv11;
            Gv[256 + c0] = gv20;  Gv[256 + c1] = gv21;
        }
    }
}

// ---------------- backward layer1 per-edge + fused force (gA0 = A0a + A0b) ----------------
__global__ __launch_bounds__(256) void tz_bwdB(const float* __restrict__ ef8, const float* __restrict__ Y1,
                                                const int2* __restrict__ cei, const int* __restrict__ nact,
                                                const float* __restrict__ R1,
                                                const float* __restrict__ su1,
                                                const float* __restrict__ gA0a, const float* __restrict__ gA0b,
                                                const float* __restrict__ gA1, const int2* __restrict__ list_r,
                                                const float* __restrict__ gefA, const float* __restrict__ gyA,
                                                const float* __restrict__ defdr, const float* __restrict__ rr,
                                                float* __restrict__ forces) {
    const int i = blockIdx.x * 256 + threadIdx.x;
    if (i >= *nact) return;
    const int2 p = list_r[i];
    const int e = p.x;
    const int sn = p.y;
    const int rv = cei[e].y;
    const float y0 = Y1[e*3+0], y1 = Y1[e*3+1], y2 = Y1[e*3+2];
    const float4 efa = ((const float4*)ef8)[e*2];
    const float4 efb = ((const float4*)ef8)[e*2+1];
    const float efv[8] = {efa.x, efa.y, efa.z, efa.w, efb.x, efb.y, efb.z, efb.w};
    float acc[8] = {0.f,0.f,0.f,0.f,0.f,0.f,0.f,0.f};
    float gg0 = 0.f, gg1 = 0.f, gg2 = 0.f;
    const float4* gmRa = (const float4*)(gA0a + (size_t)rv * KK);
    const float4* gmRb = (const float4*)(gA0b + (size_t)rv * KK);
    const float4* sjR = (const float4*)(su1 + (size_t)sn * KK);
    const float4* gxR = (const float4*)(gA1 + (size_t)rv * 384);
    const float4* gyR = gxR + 32;
    const float4* gzR = gxR + 64;
    for (int cc = 0; cc < 32; cc++) {
        const float4 gma = gmRa[cc];
        const float4 gmb = gmRb[cc];
        const float4 sj = sjR[cc];
        const float4 gx = gxR[cc];
        const float4 gy = gyR[cc];
        const float4 gz = gzR[cc];
#pragma unroll
        for (int k = 0; k < 4; k++) {
            const float gmE = ((const float*)&gma)[k] + ((const float*)&gmb)[k];
            const float sjE = ((const float*)&sj)[k];
            const float g1E = ((const float*)&gx)[k];
            const float g2E = ((const float*)&gy)[k];
            const float g3E = ((const float*)&gz)[k];
            const float q = g1E*y0 + g2E*y1 + g3E*y2;
            const float gwa = gmE * sjE;
            const float gwb = q * sjE;
            float w = 0.f;
            const int c = cc*4 + k;
#pragma unroll
            for (int b = 0; b < 8; b++) {
                const float r1a = R1[b*256 + c];
                const float r1b = R1[b*256 + 128 + c];
                acc[b] += gwa * r1a + gwb * r1b;
                w += efv[b] * r1b;
            }
            const float ws = w * sjE;
            gg0 += g1E * ws;
            gg1 += g2E * ws;
            gg2 += g3E * ws;
        }
    }
    float gr = 0.f;
#pragma unroll
    for (int b = 0; b < 8; b++) gr += (gefA[e*8+b] + acc[b]) * defdr[e*8+b];
    const float g0 = gyA[e*3+0] + gg0;
    const float g1 = gyA[e*3+1] + gg1;
    const float g2 = gyA[e*3+2] + gg2;
    const float ir = 1.f / rr[e];
    const float dot = g0*y0 + g1*y1 + g2*y2;
    const float a = gr * INV_SQ3;
    const float b2 = SQ3F * ir;
    const float c = b2 * dot * (1.f / 3.f);
    const float gv0 = a*y0 + b2*g0 - c*y0;
    const float gv1 = a*y1 + b2*g1 - c*y1;
    const float gv2 = a*y2 + b2*g2 - c*y2;
    atomAddF(&forces[rv*3+0], -gv0);
    atomAddF(&forces[rv*3+1], -gv1);
    atomAddF(&forces[rv*3+2], -gv2);
    atomAddF(&forces[sn*3+0],  gv0);
    atomAddF(&forces[sn*3+1],  gv1);
    atomAddF(&forces[sn*3+2],  gv2);
}

extern "C" void kernel_launch(void* const* d_in, const int* in_sizes, int n_in,
                              void* d_out, int out_size, void* d_ws, size_t ws_size,
                              hipStream_t stream) {
    const float* positions  = (const float*)d_in[0];
    const float* shifts     = (const float*)d_in[1];
    const int*   edge_index = (const int*)d_in[2];
    const int*   node_z     = (const int*)d_in[3];
    const int*   batch      = (const int*)d_in[4];
    const float* atomic_e   = (const float*)d_in[5];
    const float* W_embed    = (const float*)d_in[6];
    const float* R1         = (const float*)d_in[7];
    const float* W_up1      = (const float*)d_in[8];
    const float* W_mix_s1   = (const float*)d_in[9];
    const float* W_mix_v1   = (const float*)d_in[10];
    const float* W_sk_s1    = (const float*)d_in[11];
    const float* w_r1       = (const float*)d_in[12];
    const float* R2         = (const float*)d_in[13];
    const float* W_up2s     = (const float*)d_in[14];
    const float* W_up2v     = (const float*)d_in[15];
    const float* W_mix_s2   = (const float*)d_in[16];
    const float* W_sk_s2    = (const float*)d_in[17];
    const float* W_mlp      = (const float*)d_in[18];
    const float* w_out      = (const float*)d_in[19];

    float* out = (float*)d_out;
    float* ws = (float*)d_ws;
    size_t off = 0;
    float* ef    = ws + off; off += (size_t)EE * 8;
    float* defdr = ws + off; off += (size_t)EE * 8;
    float* Y1    = ws + off; off += (size_t)EE * 3;
    float* rr    = ws + off; off += (size_t)EE;
    float* gefA  = ws + off; off += (size_t)EE * 8;
    float* gyA   = ws + off; off += (size_t)EE * 3;
    float* su1   = ws + off; off += (size_t)NN * KK;
    float* s1    = ws + off; off += (size_t)NN * KK;
    float* s1u2  = ws + off; off += (size_t)NN * KK;
    float* s2    = ws + off; off += (size_t)NN * KK;
    float* g_s2  = ws + off; off += (size_t)NN * KK;
    float* g_s1  = ws + off; off += (size_t)NN * KK;
    float* vup   = ws + off; off += (size_t)NN * KK * 3;
    float* A0    = ws + off; off += (size_t)NN * KK;
    float* A0b   = ws + off; off += (size_t)NN * KK;
    float* A2    = ws + off; off += (size_t)NN * KK;
    float* Gsj2  = ws + off; off += (size_t)NN * KK;
    float* A1    = ws + off; off += (size_t)NN * KK * 3;
    float* Gvj   = ws + off; off += (size_t)NN * KK * 3;
    float* E1    = ws + off; off += 10 * KK;
    float* T1    = ws + off; off += 10 * KK;
    float* Wc    = ws + off; off += KK * KK;
    float* Wd    = ws + off; off += KK * KK;
    float* e1n   = ws + off; off += NN;
    float* e2n   = ws + off; off += NN;
    int* ip = (int*)(ws + off);
    size_t ioff = 0;
    int* deg_r = ip + ioff; ioff += NN;
    int* deg_s = ip + ioff; ioff += NN;
    int* cur_r = ip + ioff; ioff += NN;
    int* cur_s = ip + ioff; ioff += NN;
    int* zcnt  = ip + ioff; ioff += 16;
    int* zcur  = ip + ioff; ioff += 16;
    int* nact  = ip + ioff; ioff += 16;
    int* row_r = ip + ioff; ioff += NN + 2;
    int* row_s = ip + ioff; ioff += NN + 2;
    int* zrow  = ip + ioff; ioff += 16;
    int* zlist = ip + ioff; ioff += NN;
    int2* cei    = (int2*)(ip + ioff); ioff += (size_t)EE * 2;
    int2* list_r = (int2*)(ip + ioff); ioff += (size_t)EE * 2;
    int2* list_s = (int2*)(ip + ioff); ioff += (size_t)EE * 2;
    unsigned short* wp = (unsigned short*)(ip + ioff);   // 28 pairs x 32768 shorts = 1.79 MB

    const int EG = (EE + 255) / 256;                 // 625
    const int NG16 = (NN + 15) / 16;                 // 626 (16 nodes/block)
    const int BNB  = ((NN + 127) / 128) * 2;         // 158 (128-row tiles)
    const int BN3B = ((NN * 3 + 127) / 128) * 2;     // 470
    const int BS   = NE * 16;                        // 160
    const int ZB   = (out_size + 255) / 256;
    const int ZI   = (4 * NN + 48 + 255) / 256;
    tz_zero<<<ZB + ZI + 1600, 256, 0, stream>>>(out, out_size, deg_r, 4 * NN + 48, ZB, ZI,
                                                W_mix_s1, W_up2s, W_sk_s2, W_mix_s2, wp);
    tz_geomtab<<<679, 256, 0, stream>>>(positions, shifts, edge_index, ef, defdr, Y1, rr,
                                        cei, nact, deg_r, deg_s, node_z, zcnt,
                                        W_embed, W_up1, W_sk_s1, E1, T1, W_mix_v1, W_up2v, Wc,
                                        W_mix_s1, W_up2s, Wd);
    tz_scan<<<1, 1024, 0, stream>>>(deg_r, deg_s, zcnt, row_r, row_s, zrow);
    tz_fill3<<<5665 + 192, 256, 0, stream>>>(cei, nact, row_r, row_s, cur_r, cur_s,
                                             list_r, list_s, node_z, zcur, zrow, zlist,
                                             E1, T1, su1, s1, Wc, Wd, wp);
    tz_edge1<<<NG16, 256, 0, stream>>>(ef, Y1, R1, su1, row_r, list_r, A0, A1);
    tz_two<1, 0><<<BNB + BN3B, 256, 0, stream>>>(A0, wp + (size_t)0 * PAIR, s1, NN, INV_AVG,
                                                 A1, wp + (size_t)2 * PAIR, vup, NN * 3, INV_AVG, BNB);
    tz_mix<0, 0><<<BNB + BS, 256, 0, stream>>>(s1, wp + (size_t)4 * PAIR, s1u2, NN, 1.f,
                                               s1, wp + (size_t)5 * PAIR, s2, zrow, zlist, BNB);
    tz_edge2<<<NG16, 256, 0, stream>>>(ef, Y1, R2, s1u2, vup, row_r, list_r, A2);
    tz_one<1><<<BNB, 256, 0, stream>>>(A2, wp + (size_t)25 * PAIR, s2, NN, INV_AVG);
    tz_mlp<<<NN / 8, 256, 0, stream>>>(s2, W_mlp, w_out, w_r1, s1, g_s2, g_s1, e1n, e2n);
    tz_bwdmix<<<BNB + BS + 32, 256, 0, stream>>>(g_s2, wp + (size_t)26 * PAIR, A2,
                                                 wp + (size_t)15 * PAIR, g_s1,
                                                 zrow, zlist, node_z, batch, atomic_e,
                                                 e1n, e2n, out, BNB, BNB + BS);
    tz_bwdA<<<625 + NG16, 256, 0, stream>>>(ef, Y1, cei, nact, R2, A2, s1u2, vup,
                                            list_s, row_s, gefA, gyA, Gsj2, Gvj);
    tz_three<0, 0, 0><<<BN3B + BNB + BNB, 256, 0, stream>>>(
        Gvj, wp + (size_t)3 * PAIR, A1, NN * 3, INV_AVG,
        g_s1, wp + (size_t)1 * PAIR, A0, NN, INV_AVG,
        Gsj2, wp + (size_t)27 * PAIR, A0b, NN, INV_AVG, BN3B, BN3B + BNB);
    tz_bwdB<<<EG, 256, 0, stream>>>(ef, Y1, cei, nact, R1, su1, A0, A0b, A1, list_r,
                                    gefA, gyA, defdr, rr, out + GG + GG * 3);
}

// Round 10
// 273.235 us; speedup vs baseline: 1.0148x; 1.0148x over previous
//
#include <hip/hip_runtime.h>
#include <hip/hip_bf16.h>
#include <math.h>

#define NN 10000
#define EE 160000
#define KK 128
#define GG 16
#define NE 10
#define SQ3F 1.7320508075688772f
#define INV_SQ3 0.57735026918962576f
#define INV_AVG 0.0625f
#define RMAXI 0.2f

#define WPAD 136   // 128 + 8 shorts padding
#define PLANE 16384
#define PAIR 32768
// plane-pair indices: 0 ms1_T0, 1 ms1_T1, 2 c_T0, 3 c_T1, 4 u2s_T0,
// 5..14 sk2_T0[z], 15..24 sk2_T1[z], 25 ms2_T0, 26 ms2_T1, 27 d_T1

typedef __attribute__((ext_vector_type(8))) short bf16x8;
typedef __attribute__((ext_vector_type(4))) float f32x4;

__device__ __forceinline__ void atomAddF(float* p, float v) { unsafeAtomicAdd(p, v); }

__device__ __forceinline__ float waveRed(float v) {
#pragma unroll
    for (int m = 32; m >= 1; m >>= 1) v += __shfl_xor(v, m);
    return v;
}

__device__ __forceinline__ unsigned short bfrn(float x) {
    unsigned u = __float_as_uint(x);
    return (unsigned short)((u + 0x7FFFu + ((u >> 16) & 1u)) >> 16);
}
__device__ __forceinline__ float bf2f(unsigned short b) {
    return __uint_as_float(((unsigned)b) << 16);
}
__device__ __forceinline__ short bfbits(__hip_bfloat16 h) {
    union { __hip_bfloat16 b; unsigned short u; } c; c.b = h; return (short)c.u;
}

// convert one 256-elem slice of a weight matrix into hi/lo bf16 planes [c][k]
__device__ __forceinline__ void convPlane(const float* __restrict__ src, int trans,
                                          unsigned short* __restrict__ dst, int r6) {
    const int t = threadIdx.x;
    const int elem = r6 * 256 + t;          // 0..16383
    const int c = elem >> 7, k = elem & 127;
    const float v = trans ? src[c * KK + k] : src[k * KK + c];
    const unsigned short hb = bfrn(v);
    dst[c * KK + k] = hb;
    dst[PLANE + c * KK + k] = bfrn(v - bf2f(hb));
}

// ============ dense core: 64 rows x 64 cols per block, split-bf16 MFMA ============
// W planes precomputed in global; stage = pure short8 copy into [64][WPAD] LDS.
__device__ __forceinline__ void t_stagep(const unsigned short* __restrict__ P, int h,
                                         unsigned short* WhL, unsigned short* WlL) {
    const int t = threadIdx.x;
    const bf16x8* __restrict__ Sh = (const bf16x8*)(P + (size_t)(h * 64) * KK);
    const bf16x8* __restrict__ Sl = (const bf16x8*)(P + PLANE + (size_t)(h * 64) * KK);
#pragma unroll
    for (int i = 0; i < 4; i++) {
        const int v = t + i * 256;
        const int c = v >> 4, kv = v & 15;
        *(bf16x8*)&WhL[c * WPAD + kv * 8] = Sh[c * 16 + kv];
        *(bf16x8*)&WlL[c * WPAD + kv * 8] = Sl[c * 16 + kv];
    }
}

// legacy convert-stage (used only for Wc/Wd build inside tz_geomtab, TRANS=0)
__device__ __forceinline__ void t_stage_cvt(const float* __restrict__ W, int h,
                                            unsigned short* WhL, unsigned short* WlL) {
    const int t = threadIdx.x;
    for (int i = t; i < 64 * KK; i += 256) {
        const int k = i >> 6, c = i & 63;
        const float v = W[k * KK + (h * 64 + c)];
        const unsigned short hb = bfrn(v);
        WhL[c * WPAD + k] = hb;
        WlL[c * WPAD + k] = bfrn(v - bf2f(hb));
    }
}

template <int ACCUM, int GATHER>
__device__ __forceinline__ void t_compute(const float* __restrict__ in, float* __restrict__ out,
                                          int rows, float alpha, int bid_row, int h,
                                          const int* __restrict__ rowlist,
                                          const unsigned short* WhL, const unsigned short* WlL) {
    const int t = threadIdx.x;
    const int w = t >> 6;            // wave 0..3
    const int l = t & 63;
    const int lr = l & 15;           // A row within wave tile / D col within 16-col tile
    const int ls = l >> 4;           // k-slice (A) / D row group
    const int rbase = bid_row * 64 + w * 16;
    int aidx = rbase + lr;
    if (aidx > rows - 1) aidx = rows - 1;
    const int arow = GATHER ? rowlist[aidx] : aidx;
    const float* Ap = in + (size_t)arow * KK + ls * 8;
    int rowv[4];
#pragma unroll
    for (int r = 0; r < 4; r++) {
        int idx = rbase + ls * 4 + r;
        if (idx > rows - 1) idx = rows - 1;
        rowv[r] = GATHER ? rowlist[idx] : idx;
    }
    f32x4 acc[4];
#pragma unroll
    for (int ct = 0; ct < 4; ct++) { acc[ct][0] = 0.f; acc[ct][1] = 0.f; acc[ct][2] = 0.f; acc[ct][3] = 0.f; }

#pragma unroll
    for (int kc = 0; kc < 4; kc++) {               // K chunks of 32
        const float4 a0 = *(const float4*)(Ap + kc * 32);
        const float4 a1 = *(const float4*)(Ap + kc * 32 + 4);
        const float av[8] = {a0.x, a0.y, a0.z, a0.w, a1.x, a1.y, a1.z, a1.w};
        bf16x8 ah, al;
#pragma unroll
        for (int j = 0; j < 8; j++) {
            const float v = av[j];
            const __hip_bfloat16 hb = __float2bfloat16(v);
            const float hf = __bfloat162float(hb);
            ah[j] = bfbits(hb);
            al[j] = bfbits(__float2bfloat16(v - hf));
        }
#pragma unroll
        for (int ct = 0; ct < 4; ct++) {
            const int col = ct * 16 + lr;
            const bf16x8 bh = *(const bf16x8*)&WhL[col * WPAD + kc * 32 + ls * 8];
            const bf16x8 bl = *(const bf16x8*)&WlL[col * WPAD + kc * 32 + ls * 8];
            acc[ct] = __builtin_amdgcn_mfma_f32_16x16x32_bf16(ah, bh, acc[ct], 0, 0, 0);
            acc[ct] = __builtin_amdgcn_mfma_f32_16x16x32_bf16(al, bh, acc[ct], 0, 0, 0);
            acc[ct] = __builtin_amdgcn_mfma_f32_16x16x32_bf16(ah, bl, acc[ct], 0, 0, 0);
        }
    }

#pragma unroll
    for (int r = 0; r < 4; r++) {
        const int gr = rbase + ls * 4 + r;
        if (gr < rows) {
            float* orow = out + (size_t)rowv[r] * KK + h * 64;
#pragma unroll
            for (int ct = 0; ct < 4; ct++) {
                float v = acc[ct][r] * alpha;
                if (ACCUM) v += orow[ct * 16 + lr];
                orow[ct * 16 + lr] = v;
            }
        }
    }
}

// ---------------- zero-init: out + int counters + weight-plane conversion ----------------
__global__ __launch_bounds__(256) void tz_zero(float* __restrict__ out, int out_size,
                                               int* __restrict__ ints, int icount, int zb, int zi,
                                               const float* __restrict__ Wms1,
                                               const float* __restrict__ Wu2s,
                                               const float* __restrict__ Wsk2,
                                               const float* __restrict__ Wms2,
                                               unsigned short* __restrict__ wp) {
    const int t = threadIdx.x;
    if ((int)blockIdx.x < zb) {
        const int i = blockIdx.x * 256 + t;
        if (i < out_size) out[i] = 0.f;
    } else if ((int)blockIdx.x < zb + zi) {
        const int i = (blockIdx.x - zb) * 256 + t;
        if (i < icount) ints[i] = 0;
    } else {
        const int bb = blockIdx.x - (zb + zi);
        const int pr = bb >> 6, r6 = bb & 63;
        const float* src; int tr, pi;
        if (pr == 0)       { src = Wms1; tr = 0; pi = 0; }
        else if (pr == 1)  { src = Wms1; tr = 1; pi = 1; }
        else if (pr == 2)  { src = Wu2s; tr = 0; pi = 4; }
        else if (pr < 13)  { src = Wsk2 + (size_t)(pr - 3) * PLANE;  tr = 0; pi = 5 + (pr - 3); }
        else if (pr < 23)  { src = Wsk2 + (size_t)(pr - 13) * PLANE; tr = 1; pi = 15 + (pr - 13); }
        else if (pr == 23) { src = Wms2; tr = 0; pi = 25; }
        else               { src = Wms2; tr = 1; pi = 26; }
        convPlane(src, tr, wp + (size_t)pi * PAIR, r6);
    }
}

// ---------------- merged: geom (0..624) + zcount (625..664) + tables (665..674) + Wc (675..678) + Wd (679..682) ----------------
__global__ __launch_bounds__(256) void tz_geomtab(const float* __restrict__ pos, const float* __restrict__ shifts,
                            const int* __restrict__ ei,
                            float* __restrict__ ef, float* __restrict__ defdr,
                            float* __restrict__ Y1, float* __restrict__ rr,
                            int2* __restrict__ cei, int* __restrict__ nact,
                            int* __restrict__ deg_r, int* __restrict__ deg_s,
                            const int* __restrict__ z, int* __restrict__ zcnt,
                            const float* __restrict__ We, const float* __restrict__ Wup1,
                            const float* __restrict__ Wsk1,
                            float* __restrict__ E1, float* __restrict__ T1,
                            const float* __restrict__ Wmv1, const float* __restrict__ Wu2v,
                            float* __restrict__ Wc,
                            const float* __restrict__ Wms1, const float* __restrict__ Wu2s,
                            float* __restrict__ Wd) {
    __shared__ unsigned short WhL[64 * WPAD];
    __shared__ unsigned short WlL[64 * WPAD];
    const int t = threadIdx.x;
    if ((int)blockIdx.x < 625) {
        int* lcnt = (int*)WhL;
        int* lbase = ((int*)WhL) + 1;
        if (t == 0) *lcnt = 0;
        __syncthreads();
        const int e = blockIdx.x * 256 + t;
        const int sn = ei[e];
        const int rv = ei[EE + e];
        const float vx = pos[rv*3+0] - pos[sn*3+0] + shifts[e*3+0];
        const float vy = pos[rv*3+1] - pos[sn*3+1] + shifts[e*3+1];
        const float vz = pos[rv*3+2] - pos[sn*3+2] + shifts[e*3+2];
        const float r = sqrtf(vx*vx + vy*vy + vz*vz + 1e-12f);
        const float x = r * RMAXI;
        const int active = (x < 1.0f) ? 1 : 0;
        int pos_l = 0;
        if (active) pos_l = atomicAdd(lcnt, 1);
        __syncthreads();
        if (t == 0 && *lcnt > 0) *lbase = atomicAdd(nact, *lcnt);
        __syncthreads();
        if (!active) return;
        const int idx = *lbase + pos_l;
        cei[idx] = make_int2(sn, rv);
        atomicAdd(&deg_s[sn], 1);
        atomicAdd(&deg_r[rv], 1);
        const float ir = 1.0f / r;
        rr[idx] = r;
        Y1[idx*3+0] = SQ3F*vx*ir;
        Y1[idx*3+1] = SQ3F*vy*ir;
        Y1[idx*3+2] = SQ3F*vz*ir;
        const float x2 = x*x, x4 = x2*x2, x5 = x4*x, x6 = x5*x, x7 = x6*x;
        const float fc  = 1.0f - 21.0f*x5 + 35.0f*x6 - 15.0f*x7;
        const float dfc = (-105.0f*x4 + 210.0f*x5 - 105.0f*x6) * RMAXI;
        const float C = 0.63245553203367587f;
        float4 efa, efb4, da, db;
        float* efp = (float*)&efa;
        float* dp  = (float*)&da;
#pragma unroll
        for (int b = 0; b < 8; b++) {
            const float kb = (float)(b + 1) * 0.62831853071795865f;
            float sb, cb;
            sincosf(kb * r, &sb, &cb);
            const float bess  = C * sb * ir;
            const float dbess = C * ir * (kb * cb - sb * ir);
            if (b == 4) { efp = (float*)&efb4; dp = (float*)&db; }
            efp[b & 3] = bess * fc;
            dp[b & 3]  = dbess * fc + bess * dfc;
        }
        ((float4*)ef)[idx*2]    = efa;
        ((float4*)ef)[idx*2+1]  = efb4;
        ((float4*)defdr)[idx*2]   = da;
        ((float4*)defdr)[idx*2+1] = db;
    } else if ((int)blockIdx.x < 665) {
        int* h = (int*)WhL;
        if (t < NE) h[t] = 0;
        __syncthreads();
        const int n = (blockIdx.x - 625) * 256 + t;
        if (n < NN) atomicAdd(&h[z[n]], 1);
        __syncthreads();
        if (t < NE && h[t] > 0) atomicAdd(&zcnt[t], h[t]);
    } else if ((int)blockIdx.x < 675) {
        const int zz = blockIdx.x - 665;
        if (t < KK) {
            float a = 0.f, bv = 0.f;
            for (int c = 0; c < KK; c++) {
                const float w = We[zz*KK + c];
                a  += w * Wup1[c*KK + t];
                bv += w * Wsk1[(size_t)(zz*KK + c)*KK + t];
            }
            E1[zz*KK + t] = a;
            T1[zz*KK + t] = bv;
        }
    } else if ((int)blockIdx.x < 679) {
        const int b = blockIdx.x - 675;      // 0..3
        const int h = b & 1;
        t_stage_cvt(Wu2v, h, WhL, WlL);      // Wc = Wmv1 @ Wu2v
        __syncthreads();
        t_compute<0, 0>(Wmv1, Wc, KK, 1.f, b >> 1, h, nullptr, WhL, WlL);
    } else {
        const int b = blockIdx.x - 679;      // 0..3
        const int h = b & 1;
        t_stage_cvt(Wu2s, h, WhL, WlL);      // Wd = Wms1 @ Wu2s
        __syncthreads();
        t_compute<0, 0>(Wms1, Wd, KK, 1.f, b >> 1, h, nullptr, WhL, WlL);
    }
}

// ---------------- packed scan via wave shuffles (deg_r lo32, deg_s hi32), 2 barriers ----------------
__global__ __launch_bounds__(1024) void tz_scan(const int* __restrict__ deg_r, const int* __restrict__ deg_s,
                                               const int* __restrict__ zcnt,
                                               int* __restrict__ row_r, int* __restrict__ row_s,
                                               int* __restrict__ zrow) {
    __shared__ unsigned long long wsum[16];
    __shared__ unsigned long long wscan[16];
    const int t = threadIdx.x;
    const int lane = t & 63;
    const int wid = t >> 6;
    if (t == 0) {
        int s = 0;
        for (int i = 0; i < NE; i++) { zrow[i] = s; s += zcnt[i]; }
        zrow[NE] = s;
    }
    const int base = t * 10;
    unsigned long long loc[10];
    unsigned long long s = 0;
#pragma unroll
    for (int k = 0; k < 10; k++) {
        loc[k] = s;
        if (base + k < NN)
            s += ((unsigned long long)(unsigned)deg_s[base + k] << 32) | (unsigned)deg_r[base + k];
    }
    unsigned long long x = s;
#pragma unroll
    for (int off = 1; off < 64; off <<= 1) {
        const unsigned long long y = __shfl_up((long long)x, off);
        if (lane >= off) x += y;
    }
    if (lane == 63) wsum[wid] = x;
    __syncthreads();
    if (wid == 0 && lane < 16) {
        unsigned long long v = wsum[lane];
#pragma unroll
        for (int off = 1; off < 16; off <<= 1) {
            const unsigned long long y = __shfl_up((long long)v, off);
            if (lane >= off) v += y;
        }
        wscan[lane] = v;
    }
    __syncthreads();
    const unsigned long long woff = (wid > 0) ? wscan[wid - 1] : 0ull;
    const unsigned long long bex = woff + x - s;   // exclusive prefix for this thread
#pragma unroll
    for (int k = 0; k < 10; k++)
        if (base + k < NN) {
            const unsigned long long p = bex + loc[k];
            row_r[base + k] = (int)(p & 0xffffffffu);
            row_s[base + k] = (int)(p >> 32);
        }
    if (t == 1023) {
        const unsigned long long p = wscan[15];
        row_r[NN] = (int)(p & 0xffffffffu);
        row_s[NN] = (int)(p >> 32);
    }
}

// ---------------- merged: CSR fill (0..624) + zfill (625..664) + zinit (665..5664) + Wc/Wd planes ----------------
__global__ __launch_bounds__(256) void tz_fill3(const int2* __restrict__ cei, const int* __restrict__ nact,
                       const int* __restrict__ row_r, const int* __restrict__ row_s,
                       int* __restrict__ cur_r, int* __restrict__ cur_s,
                       int2* __restrict__ list_r, int2* __restrict__ list_s,
                       const int* __restrict__ z, int* __restrict__ zcur,
                       const int* __restrict__ zrow, int* __restrict__ zlist,
                       const float* __restrict__ E1, const float* __restrict__ T1,
                       float* __restrict__ su1, float* __restrict__ s1,
                       const float* __restrict__ Wc, const float* __restrict__ Wd,
                       unsigned short* __restrict__ wp) {
    const int t = threadIdx.x;
    if ((int)blockIdx.x < 625) {
        const int i = blockIdx.x * 256 + t;
        if (i >= *nact) return;
        const int2 p = cei[i];
        const int pr = atomicAdd(&cur_r[p.y], 1);
        list_r[row_r[p.y] + pr] = make_int2(i, p.x);
        const int ps = atomicAdd(&cur_s[p.x], 1);
        list_s[row_s[p.x] + ps] = make_int2(i, p.y);
    } else if ((int)blockIdx.x < 665) {
        __shared__ int cnt[NE];
        __shared__ int base[NE];
        if (t < NE) cnt[t] = 0;
        __syncthreads();
        const int n = (blockIdx.x - 625) * 256 + t;
        int pos = -1, zz = 0;
        if (n < NN) { zz = z[n]; pos = atomicAdd(&cnt[zz], 1); }
        __syncthreads();
        if (t < NE && cnt[t] > 0) base[t] = atomicAdd(&zcur[t], cnt[t]);
        __syncthreads();
        if (n < NN) zlist[zrow[zz] + base[zz] + pos] = n;
    } else if ((int)blockIdx.x < 5665) {
        const int i = (blockIdx.x - 665) * 256 + t;
        if (i >= NN * KK) return;
        const int base = z[i >> 7] * KK + (i & 127);
        su1[i] = E1[base];
        s1[i]  = T1[base];
    } else {
        const int bb = blockIdx.x - 5665;
        const int pr = bb >> 6, r6 = bb & 63;
        if (pr == 0)      convPlane(Wc, 0, wp + (size_t)2 * PAIR, r6);
        else if (pr == 1) convPlane(Wc, 1, wp + (size_t)3 * PAIR, r6);
        else              convPlane(Wd, 1, wp + (size_t)27 * PAIR, r6);
    }
}

// ---- single dense op ----
template <int ACCUM>
__global__ __launch_bounds__(256) void tz_one(const float* __restrict__ in, const unsigned short* __restrict__ P,
                                              float* __restrict__ out, int rows, float alpha) {
    __shared__ unsigned short WhL[64 * WPAD];
    __shared__ unsigned short WlL[64 * WPAD];
    const int h = blockIdx.x & 1;
    t_stagep(P, h, WhL, WlL);
    __syncthreads();
    t_compute<ACCUM, 0>(in, out, rows, alpha, blockIdx.x >> 1, h, nullptr, WhL, WlL);
}

// ---- two dense ops, one dispatch ----
template <int AA, int AB>
__global__ __launch_bounds__(256) void tz_two(
        const float* __restrict__ inA, const unsigned short* __restrict__ PA, float* __restrict__ outA,
        int rowsA, float alphaA,
        const float* __restrict__ inB, const unsigned short* __restrict__ PB, float* __restrict__ outB,
        int rowsB, float alphaB, int blocksA) {
    __shared__ unsigned short WhL[64 * WPAD];
    __shared__ unsigned short WlL[64 * WPAD];
    if ((int)blockIdx.x < blocksA) {
        const int h = blockIdx.x & 1;
        t_stagep(PA, h, WhL, WlL);
        __syncthreads();
        t_compute<AA, 0>(inA, outA, rowsA, alphaA, blockIdx.x >> 1, h, nullptr, WhL, WlL);
    } else {
        const int b = blockIdx.x - blocksA;
        const int h = b & 1;
        t_stagep(PB, h, WhL, WlL);
        __syncthreads();
        t_compute<AB, 0>(inB, outB, rowsB, alphaB, b >> 1, h, nullptr, WhL, WlL);
    }
}

// ---- three dense ops, one dispatch ----
template <int AA, int AB, int AC>
__global__ __launch_bounds__(256) void tz_three(
        const float* __restrict__ inA, const unsigned short* __restrict__ PA, float* __restrict__ outA,
        int rowsA, float alphaA,
        const float* __restrict__ inB, const unsigned short* __restrict__ PB, float* __restrict__ outB,
        int rowsB, float alphaB,
        const float* __restrict__ inC, const unsigned short* __restrict__ PC, float* __restrict__ outC,
        int rowsC, float alphaC, int blocksA, int blocksAB) {
    __shared__ unsigned short WhL[64 * WPAD];
    __shared__ unsigned short WlL[64 * WPAD];
    if ((int)blockIdx.x < blocksA) {
        const int h = blockIdx.x & 1;
        t_stagep(PA, h, WhL, WlL);
        __syncthreads();
        t_compute<AA, 0>(inA, outA, rowsA, alphaA, blockIdx.x >> 1, h, nullptr, WhL, WlL);
    } else if ((int)blockIdx.x < blocksAB) {
        const int b = blockIdx.x - blocksA;
        const int h = b & 1;
        t_stagep(PB, h, WhL, WlL);
        __syncthreads();
        t_compute<AB, 0>(inB, outB, rowsB, alphaB, b >> 1, h, nullptr, WhL, WlL);
    } else {
        const int b = blockIdx.x - blocksAB;
        const int h = b & 1;
        t_stagep(PC, h, WhL, WlL);
        __syncthreads();
        t_compute<AC, 0>(inC, outC, rowsC, alphaC, b >> 1, h, nullptr, WhL, WlL);
    }
}

// ---- dense op + per-z skip buckets, one dispatch ----
template <int AA, int AS>
__global__ __launch_bounds__(256) void tz_mix(
        const float* __restrict__ inA, const unsigned short* __restrict__ PA, float* __restrict__ outA,
        int rowsA, float alphaA,
        const float* __restrict__ inS, const unsigned short* __restrict__ PSbase, float* __restrict__ outS,
        const int* __restrict__ zrow, const int* __restrict__ zlist, int blocksA) {
    __shared__ unsigned short WhL[64 * WPAD];
    __shared__ unsigned short WlL[64 * WPAD];
    if ((int)blockIdx.x < blocksA) {
        const int h = blockIdx.x & 1;
        t_stagep(PA, h, WhL, WlL);
        __syncthreads();
        t_compute<AA, 0>(inA, outA, rowsA, alphaA, blockIdx.x >> 1, h, nullptr, WhL, WlL);
    } else {
        const int sbid = blockIdx.x - blocksA;
        const int zz = sbid % NE;
        const int q = sbid / NE;            // 0..31
        const int h = q & 1;
        const int ch0 = q >> 1;             // 0..15
        const int beg = zrow[zz];
        const int cnt = zrow[zz + 1] - beg;
        if (ch0 * 64 >= cnt) return;
        t_stagep(PSbase + (size_t)zz * PAIR, h, WhL, WlL);
        __syncthreads();
        for (int ch = ch0; ch * 64 < cnt; ch += 16)
            t_compute<AS, 1>(inS, outS, cnt, 1.f, ch, h, zlist + beg, WhL, WlL);
    }
}

// ---- backward bundle: dense g_A2 + skip bwd accum + energy (last 32) ----
__global__ __launch_bounds__(256) void tz_bwdmix(
        const float* __restrict__ g_s2, const unsigned short* __restrict__ Pms2t, float* __restrict__ gA2,
        const unsigned short* __restrict__ Psk2t, float* __restrict__ g_s1,
        const int* __restrict__ zrow, const int* __restrict__ zlist,
        const int* __restrict__ z, const int* __restrict__ batch, const float* __restrict__ ae,
        const float* __restrict__ e1n, const float* __restrict__ e2n, float* __restrict__ out,
        int blocksA, int blocksAB) {
    __shared__ unsigned short WhL[64 * WPAD];
    __shared__ unsigned short WlL[64 * WPAD];
    const int t = threadIdx.x;
    if ((int)blockIdx.x < blocksA) {
        const int h = blockIdx.x & 1;
        t_stagep(Pms2t, h, WhL, WlL);
        __syncthreads();
        t_compute<0, 0>(g_s2, gA2, NN, INV_AVG, blockIdx.x >> 1, h, nullptr, WhL, WlL);
    } else if ((int)blockIdx.x < blocksAB) {
        const int sbid = blockIdx.x - blocksA;
        const int zz = sbid % NE;
        const int q = sbid / NE;            // 0..31
        const int h = q & 1;
        const int ch0 = q >> 1;             // 0..15
        const int beg = zrow[zz];
        const int cnt = zrow[zz + 1] - beg;
        if (ch0 * 64 >= cnt) return;
        t_stagep(Psk2t + (size_t)zz * PAIR, h, WhL, WlL);
        __syncthreads();
        for (int ch = ch0; ch * 64 < cnt; ch += 16)
            t_compute<1, 1>(g_s2, g_s1, cnt, 1.f, ch, h, zlist + beg, WhL, WlL);
    } else {
        float* bins = (float*)WhL;
        for (int i = t; i < GG * 4; i += 256) bins[i] = 0.f;
        __syncthreads();
        const int idx = (blockIdx.x - blocksAB) * 256 + t;
        const int stride = 32 * 256;
        for (int n = idx; n < NN; n += stride) {
            const int b = batch[n];
            const float v0 = ae[z[n]];
            const float v1 = e1n[n];
            const float v2 = e2n[n];
            atomicAdd(&bins[b*4+0], v0 + v1 + v2);
            atomicAdd(&bins[b*4+1], v0);
            atomicAdd(&bins[b*4+2], v1);
            atomicAdd(&bins[b*4+3], v2);
        }
        __syncthreads();
        for (int i = t; i < GG * 4; i += 256) {
            const float v = bins[i];
            if (v != 0.f) {
                const int b = i >> 2;
                const int k = i & 3;
                float* dst = (k == 0) ? &out[b] : &out[GG + b*3 + (k - 1)];
                atomAddF(dst, v);
            }
        }
    }
}

// ---------------- edge pass 1 (rcv-centric gather, 16 nodes/block) ----------------
__global__ __launch_bounds__(256) void tz_edge1(const float* __restrict__ ef, const float* __restrict__ Y1,
                                                 const float* __restrict__ R1, const float* __restrict__ su1,
                                                 const int* __restrict__ row_r, const int2* __restrict__ list_r,
                                                 float* __restrict__ A0, float* __restrict__ A1) {
    __shared__ float RL[2048];
    for (int i = threadIdx.x; i < 2048; i += 256) RL[i] = R1[i];
    __syncthreads();
    const int lane = threadIdx.x & 63;
    const int sub = threadIdx.x >> 6;
    const int c0 = lane;
    const int c1 = lane + 64;
    for (int cc = 0; cc < 4; cc++) {
        const int n = blockIdx.x * 16 + cc * 4 + sub;
        if (n >= NN) break;
        float a00 = 0.f, a01 = 0.f;
        float ax0 = 0.f, ax1 = 0.f, ay0 = 0.f, ay1 = 0.f, az0 = 0.f, az1 = 0.f;
        const int beg = row_r[n];
        const int end = row_r[n + 1];
        for (int i = beg; i < end; i++) {
            const int2 p = list_r[i];
            const int e = p.x;
            const int sn = p.y;
            const float4 efa = ((const float4*)ef)[e*2];
            const float4 efb4 = ((const float4*)ef)[e*2+1];
            const float y0 = Y1[e*3+0], y1 = Y1[e*3+1], y2 = Y1[e*3+2];
            float wa0 = 0.f, wa1 = 0.f, wb0 = 0.f, wb1 = 0.f;
            const float* eb = (const float*)&efa;
#pragma unroll
            for (int b = 0; b < 8; b++) {
                if (b == 4) eb = (const float*)&efb4;
                const float v = eb[b & 3];
                wa0 += v * RL[b*256 + c0];
                wb0 += v * RL[b*256 + 128 + c0];
                wa1 += v * RL[b*256 + c1];
                wb1 += v * RL[b*256 + 128 + c1];
            }
            const float sj0 = su1[sn*KK + c0];
            const float sj1 = su1[sn*KK + c1];
            a00 += wa0 * sj0;
            a01 += wa1 * sj1;
            const float mb0 = wb0 * sj0;
            const float mb1 = wb1 * sj1;
            ax0 += mb0*y0; ax1 += mb1*y0;
            ay0 += mb0*y1; ay1 += mb1*y1;
            az0 += mb0*y2; az1 += mb1*y2;
        }
        A0[(size_t)n*KK + c0] = a00;
        A0[(size_t)n*KK + c1] = a01;
        float* A1r = A1 + (size_t)n * 384;
        A1r[c0] = ax0;        A1r[c1] = ax1;
        A1r[128 + c0] = ay0;  A1r[128 + c1] = ay1;
        A1r[256 + c0] = az0;  A1r[256 + c1] = az1;
    }
}

// ---------------- edge pass 2 (rcv-centric gather, 16 nodes/block) ----------------
__global__ __launch_bounds__(256) void tz_edge2(const float* __restrict__ ef, const float* __restrict__ Y1,
                                                 const float* __restrict__ R2, const float* __restrict__ s1u2,
                                                 const float* __restrict__ vup,
                                                 const int* __restrict__ row_r, const int2* __restrict__ list_r,
                                                 float* __restrict__ A2) {
    __shared__ float RL[2048];
    for (int i = threadIdx.x; i < 2048; i += 256) RL[i] = R2[(i >> 8) * 512 + (i & 255)];
    __syncthreads();
    const int lane = threadIdx.x & 63;
    const int sub = threadIdx.x >> 6;
    const int c0 = lane;
    const int c1 = lane + 64;
    for (int cc = 0; cc < 4; cc++) {
        const int n = blockIdx.x * 16 + cc * 4 + sub;
        if (n >= NN) break;
        float a0 = 0.f, a1 = 0.f;
        const int beg = row_r[n];
        const int end = row_r[n + 1];
        for (int i = beg; i < end; i++) {
            const int2 p = list_r[i];
            const int e = p.x;
            const int sn = p.y;
            const float4 efa = ((const float4*)ef)[e*2];
            const float4 efb4 = ((const float4*)ef)[e*2+1];
            const float y0 = Y1[e*3+0], y1 = Y1[e*3+1], y2 = Y1[e*3+2];
            float w00_0 = 0.f, w00_1 = 0.f, w110_0 = 0.f, w110_1 = 0.f;
            const float* eb = (const float*)&efa;
#pragma unroll
            for (int b = 0; b < 8; b++) {
                if (b == 4) eb = (const float*)&efb4;
                const float v = eb[b & 3];
                w00_0  += v * RL[b*256 + c0];
                w110_0 += v * RL[b*256 + 128 + c0];
                w00_1  += v * RL[b*256 + c1];
                w110_1 += v * RL[b*256 + 128 + c1];
            }
            const float sj0 = s1u2[sn*KK + c0];
            const float sj1 = s1u2[sn*KK + c1];
            const float* vu = vup + (size_t)sn * 384;
            const float tt0 = (vu[c0]*y0 + vu[128 + c0]*y1 + vu[256 + c0]*y2) * INV_SQ3;
            const float tt1 = (vu[c1]*y0 + vu[128 + c1]*y1 + vu[256 + c1]*y2) * INV_SQ3;
            a0 += w00_0 * sj0 + w110_0 * tt0;
            a1 += w00_1 * sj1 + w110_1 * tt1;
        }
        A2[(size_t)n*KK + c0] = a0;
        A2[(size_t)n*KK + c1] = a1;
    }
}

// ---------------- MLP energy head + e1 + backward seed (8 nodes/block, W staged once) ----------------
__global__ __launch_bounds__(256) void tz_mlp(const float* __restrict__ s2, const float* __restrict__ W_mlp,
                                             const float* __restrict__ w_out, const float* __restrict__ w_r1,
                                             const float* __restrict__ s1,
                                             float* __restrict__ g_s2, float* __restrict__ g_s1,
                                             float* __restrict__ e1n, float* __restrict__ e2n) {
    __shared__ float WmL[KK * 17];
    __shared__ float s2L[2][KK];
    __shared__ float part[256];
    __shared__ float ghL[2][16];
    __shared__ float eL[2][16];
    __shared__ float pw[4];
    const int t = threadIdx.x;
    const int grp = t >> 7;
    const int tl = t & 127;
    for (int i = t; i < KK * 16; i += 256) WmL[(i >> 4) * 17 + (i & 15)] = W_mlp[i];
    const float wr = w_r1[tl];
    const float wo = (tl < 16) ? w_out[tl] : 0.f;
    __syncthreads();
    for (int it = 0; it < 4; ++it) {
        const int n = blockIdx.x * 8 + it * 2 + grp;
        s2L[grp][tl] = s2[(size_t)n * KK + tl];
        float p = s1[(size_t)n * KK + tl] * wr;
        p = waveRed(p);
        if ((t & 63) == 0) pw[t >> 6] = p;
        __syncthreads();
        {
            const int j = tl & 15;
            const int seg = tl >> 4;
            float pr = 0.f;
#pragma unroll
            for (int c = 0; c < 16; c++) pr += s2L[grp][seg*16 + c] * WmL[(seg*16 + c) * 17 + j];
            part[t] = pr;
        }
        __syncthreads();
        if (tl < 16) {
            float hh = 0.f;
#pragma unroll
            for (int s = 0; s < 8; s++) hh += part[grp*128 + s*16 + tl];
            const float sg = 1.f / (1.f + expf(-hh));
            eL[grp][tl]  = hh * sg * wo;
            ghL[grp][tl] = wo * sg * (1.f + hh * (1.f - sg));
        }
        __syncthreads();
        if (tl == 0) {
            float e = 0.f;
#pragma unroll
            for (int j = 0; j < 16; j++) e += eL[grp][j];
            e2n[n] = e;
            e1n[n] = pw[grp*2] + pw[grp*2+1];
        }
        float g = 0.f;
#pragma unroll
        for (int j = 0; j < 16; j++) g += ghL[grp][j] * WmL[tl * 17 + j];
        g_s2[(size_t)n * KK + tl] = g;
        g_s1[(size_t)n * KK + tl] = wr;
        __syncthreads();
    }
}

// ---------------- merged backward layer2: per-edge (0..624) + node sums (625.., 16 nodes/block) ----------------
__global__ __launch_bounds__(256) void tz_bwdA(const float* __restrict__ ef8, const float* __restrict__ Y1,
                                                const int2* __restrict__ cei, const int* __restrict__ nact,
                                                const float* __restrict__ R2,
                                                const float* __restrict__ gA2, const float* __restrict__ s1u2,
                                                const float* __restrict__ vup,
                                                const int2* __restrict__ list_s, const int* __restrict__ row_s,
                                                float* __restrict__ gefA, float* __restrict__ gyA,
                                                float* __restrict__ Gsj2, float* __restrict__ Gvj) {
    __shared__ float RL[2048];
    const int t = threadIdx.x;
    if ((int)blockIdx.x < 625) {
        const int i = blockIdx.x * 256 + t;
        if (i >= *nact) return;
        const int2 p = list_s[i];
        const int e = p.x;
        const int rv = p.y;
        const int sn = cei[e].x;
        const float y0 = Y1[e*3+0], y1 = Y1[e*3+1], y2 = Y1[e*3+2];
        const float4 efa = ((const float4*)ef8)[e*2];
        const float4 efb = ((const float4*)ef8)[e*2+1];
        const float efv[8] = {efa.x, efa.y, efa.z, efa.w, efb.x, efb.y, efb.z, efb.w};
        float acc[8] = {0.f,0.f,0.f,0.f,0.f,0.f,0.f,0.f};
        float g0 = 0.f, g1 = 0.f, g2 = 0.f;
        const float4* gaR = (const float4*)(gA2 + (size_t)rv * KK);
        const float4* sjR = (const float4*)(s1u2 + (size_t)sn * KK);
        const float4* vxR = (const float4*)(vup + (size_t)sn * 384);
        const float4* vyR = vxR + 32;
        const float4* vzR = vxR + 64;
        for (int cc = 0; cc < 32; cc++) {
            const float4 ga = gaR[cc];
            const float4 sj = sjR[cc];
            const float4 vx = vxR[cc];
            const float4 vy = vyR[cc];
            const float4 vz = vzR[cc];
#pragma unroll
            for (int k = 0; k < 4; k++) {
                const float gaE = ((const float*)&ga)[k];
                const float sjE = ((const float*)&sj)[k];
                const float vxE = ((const float*)&vx)[k];
                const float vyE = ((const float*)&vy)[k];
                const float vzE = ((const float*)&vz)[k];
                const float tt = (vxE*y0 + vyE*y1 + vzE*y2) * INV_SQ3;
                const float gw00 = gaE * sjE;
                const float gw110 = gaE * tt;
                float w110 = 0.f;
                const int c = cc*4 + k;
#pragma unroll
                for (int b = 0; b < 8; b++) {
                    const float r2a = R2[b*512 + c];
                    const float r2b = R2[b*512 + 128 + c];
                    acc[b] += gw00 * r2a + gw110 * r2b;
                    w110 += efv[b] * r2b;
                }
                const float gt = gaE * w110;
                g0 += gt * vxE;
                g1 += gt * vyE;
                g2 += gt * vzE;
            }
        }
        ((float4*)gefA)[e*2]   = make_float4(acc[0], acc[1], acc[2], acc[3]);
        ((float4*)gefA)[e*2+1] = make_float4(acc[4], acc[5], acc[6], acc[7]);
        gyA[e*3+0] = g0 * INV_SQ3;
        gyA[e*3+1] = g1 * INV_SQ3;
        gyA[e*3+2] = g2 * INV_SQ3;
    } else {
        for (int i = t; i < 2048; i += 256) RL[i] = R2[(i >> 8) * 512 + (i & 255)];
        __syncthreads();
        const int lane = t & 63;
        const int sub = t >> 6;
        const int c0 = lane;
        const int c1 = lane + 64;
        for (int cc2 = 0; cc2 < 4; cc2++) {
            const int sn = (blockIdx.x - 625) * 16 + cc2 * 4 + sub;
            if (sn >= NN) break;
            float gs0 = 0.f, gs1 = 0.f;
            float gv00 = 0.f, gv01 = 0.f, gv10 = 0.f, gv11 = 0.f, gv20 = 0.f, gv21 = 0.f;
            const int beg = row_s[sn];
            const int end = row_s[sn + 1];
            for (int i = beg; i < end; i++) {
                const int2 p = list_s[i];
                const int e = p.x;
                const int rv = p.y;
                const float4 efa = ((const float4*)ef8)[e*2];
                const float4 efb4 = ((const float4*)ef8)[e*2+1];
                const float y0 = Y1[e*3+0], y1 = Y1[e*3+1], y2 = Y1[e*3+2];
                float w00_0 = 0.f, w00_1 = 0.f, w110_0 = 0.f, w110_1 = 0.f;
                const float* eb = (const float*)&efa;
#pragma unroll
                for (int b = 0; b < 8; b++) {
                    if (b == 4) eb = (const float*)&efb4;
                    const float v = eb[b & 3];
                    w00_0  += v * RL[b*256 + c0];
                    w110_0 += v * RL[b*256 + 128 + c0];
                    w00_1  += v * RL[b*256 + c1];
                    w110_1 += v * RL[b*256 + 128 + c1];
                }
                const float ga0 = gA2[(size_t)rv*KK + c0];
                const float ga1 = gA2[(size_t)rv*KK + c1];
                gs0 += ga0 * w00_0;
                gs1 += ga1 * w00_1;
                const float gts0 = ga0 * w110_0 * INV_SQ3;
                const float gts1 = ga1 * w110_1 * INV_SQ3;
                gv00 += gts0*y0; gv01 += gts1*y0;
                gv10 += gts0*y1; gv11 += gts1*y1;
                gv20 += gts0*y2; gv21 += gts1*y2;
            }
            Gsj2[(size_t)sn*KK + c0] = gs0;
            Gsj2[(size_t)sn*KK + c1] = gs1;
            float* Gv = Gvj + (size_t)sn * 384;
            Gv[c0] = gv00;        Gv[c1] = gv01;
            Gv[128 + c0] = gv10;  Gv[128 + c1] = gv11;
            Gv[256 + c0] = gv20;  Gv[256 + c1] = gv21;
        }
    }
}

// ---------------- backward layer1 per-edge + fused force (gA0 = A0a + A0b) ----------------
__global__ __launch_bounds__(256) void tz_bwdB(const float* __restrict__ ef8, const float* __restrict__ Y1,
                                                const int2* __restrict__ cei, const int* __restrict__ nact,
                                                const float* __restrict__ R1,
                                                const float* __restrict__ su1,
                                                const float* __restrict__ gA0a, const float* __restrict__ gA0b,
                                                const float* __restrict__ gA1, const int2* __restrict__ list_r,
                                                const float* __restrict__ gefA, const float* __restrict__ gyA,
                                                const float* __restrict__ defdr, const float* __restrict__ rr,
                                                float* __restrict__ forces) {
    const int i = blockIdx.x * 256 + threadIdx.x;
    if (i >= *nact) return;
    const int2 p = list_r[i];
    const int e = p.x;
    const int sn = p.y;
    const int rv = cei[e].y;
    const float y0 = Y1[e*3+0], y1 = Y1[e*3+1], y2 = Y1[e*3+2];
    const float4 efa = ((const float4*)ef8)[e*2];
    const float4 efb = ((const float4*)ef8)[e*2+1];
    const float efv[8] = {efa.x, efa.y, efa.z, efa.w, efb.x, efb.y, efb.z, efb.w};
    float acc[8] = {0.f,0.f,0.f,0.f,0.f,0.f,0.f,0.f};
    float gg0 = 0.f, gg1 = 0.f, gg2 = 0.f;
    const float4* gmRa = (const float4*)(gA0a + (size_t)rv * KK);
    const float4* gmRb = (const float4*)(gA0b + (size_t)rv * KK);
    const float4* sjR = (const float4*)(su1 + (size_t)sn * KK);
    const float4* gxR = (const float4*)(gA1 + (size_t)rv * 384);
    const float4* gyR = gxR + 32;
    const float4* gzR = gxR + 64;
    for (int cc = 0; cc < 32; cc++) {
        const float4 gma = gmRa[cc];
        const float4 gmb = gmRb[cc];
        const float4 sj = sjR[cc];
        const float4 gx = gxR[cc];
        const float4 gy = gyR[cc];
        const float4 gz = gzR[cc];
#pragma unroll
        for (int k = 0; k < 4; k++) {
            const float gmE = ((const float*)&gma)[k] + ((const float*)&gmb)[k];
            const float sjE = ((const float*)&sj)[k];
            const float g1E = ((const float*)&gx)[k];
            const float g2E = ((const float*)&gy)[k];
            const float g3E = ((const float*)&gz)[k];
            const float q = g1E*y0 + g2E*y1 + g3E*y2;
            const float gwa = gmE * sjE;
            const float gwb = q * sjE;
            float w = 0.f;
            const int c = cc*4 + k;
#pragma unroll
            for (int b = 0; b < 8; b++) {
                const float r1a = R1[b*256 + c];
                const float r1b = R1[b*256 + 128 + c];
                acc[b] += gwa * r1a + gwb * r1b;
                w += efv[b] * r1b;
            }
            const float ws = w * sjE;
            gg0 += g1E * ws;
            gg1 += g2E * ws;
            gg2 += g3E * ws;
        }
    }
    float gr = 0.f;
#pragma unroll
    for (int b = 0; b < 8; b++) gr += (gefA[e*8+b] + acc[b]) * defdr[e*8+b];
    const float g0 = gyA[e*3+0] + gg0;
    const float g1 = gyA[e*3+1] + gg1;
    const float g2 = gyA[e*3+2] + gg2;
    const float ir = 1.f / rr[e];
    const float dot = g0*y0 + g1*y1 + g2*y2;
    const float a = gr * INV_SQ3;
    const float b2 = SQ3F * ir;
    const float c = b2 * dot * (1.f / 3.f);
    const float gv0 = a*y0 + b2*g0 - c*y0;
    const float gv1 = a*y1 + b2*g1 - c*y1;
    const float gv2 = a*y2 + b2*g2 - c*y2;
    atomAddF(&forces[rv*3+0], -gv0);
    atomAddF(&forces[rv*3+1], -gv1);
    atomAddF(&forces[rv*3+2], -gv2);
    atomAddF(&forces[sn*3+0],  gv0);
    atomAddF(&forces[sn*3+1],  gv1);
    atomAddF(&forces[sn*3+2],  gv2);
}

extern "C" void kernel_launch(void* const* d_in, const int* in_sizes, int n_in,
                              void* d_out, int out_size, void* d_ws, size_t ws_size,
                              hipStream_t stream) {
    const float* positions  = (const float*)d_in[0];
    const float* shifts     = (const float*)d_in[1];
    const int*   edge_index = (const int*)d_in[2];
    const int*   node_z     = (const int*)d_in[3];
    const int*   batch      = (const int*)d_in[4];
    const float* atomic_e   = (const float*)d_in[5];
    const float* W_embed    = (const float*)d_in[6];
    const float* R1         = (const float*)d_in[7];
    const float* W_up1      = (const float*)d_in[8];
    const float* W_mix_s1   = (const float*)d_in[9];
    const float* W_mix_v1   = (const float*)d_in[10];
    const float* W_sk_s1    = (const float*)d_in[11];
    const float* w_r1       = (const float*)d_in[12];
    const float* R2         = (const float*)d_in[13];
    const float* W_up2s     = (const float*)d_in[14];
    const float* W_up2v     = (const float*)d_in[15];
    const float* W_mix_s2   = (const float*)d_in[16];
    const float* W_sk_s2    = (const float*)d_in[17];
    const float* W_mlp      = (const float*)d_in[18];
    const float* w_out      = (const float*)d_in[19];

    float* out = (float*)d_out;
    float* ws = (float*)d_ws;
    size_t off = 0;
    float* ef    = ws + off; off += (size_t)EE * 8;
    float* defdr = ws + off; off += (size_t)EE * 8;
    float* Y1    = ws + off; off += (size_t)EE * 3;
    float* rr    = ws + off; off += (size_t)EE;
    float* gefA  = ws + off; off += (size_t)EE * 8;
    float* gyA   = ws + off; off += (size_t)EE * 3;
    float* su1   = ws + off; off += (size_t)NN * KK;
    float* s1    = ws + off; off += (size_t)NN * KK;
    float* s1u2  = ws + off; off += (size_t)NN * KK;
    float* s2    = ws + off; off += (size_t)NN * KK;
    float* g_s2  = ws + off; off += (size_t)NN * KK;
    float* g_s1  = ws + off; off += (size_t)NN * KK;
    float* vup   = ws + off; off += (size_t)NN * KK * 3;
    float* A0    = ws + off; off += (size_t)NN * KK;
    float* A0b   = ws + off; off += (size_t)NN * KK;
    float* A2    = ws + off; off += (size_t)NN * KK;
    float* Gsj2  = ws + off; off += (size_t)NN * KK;
    float* A1    = ws + off; off += (size_t)NN * KK * 3;
    float* Gvj   = ws + off; off += (size_t)NN * KK * 3;
    float* E1    = ws + off; off += 10 * KK;
    float* T1    = ws + off; off += 10 * KK;
    float* Wc    = ws + off; off += KK * KK;
    float* Wd    = ws + off; off += KK * KK;
    float* e1n   = ws + off; off += NN;
    float* e2n   = ws + off; off += NN;
    int* ip = (int*)(ws + off);
    size_t ioff = 0;
    int* deg_r = ip + ioff; ioff += NN;
    int* deg_s = ip + ioff; ioff += NN;
    int* cur_r = ip + ioff; ioff += NN;
    int* cur_s = ip + ioff; ioff += NN;
    int* zcnt  = ip + ioff; ioff += 16;
    int* zcur  = ip + ioff; ioff += 16;
    int* nact  = ip + ioff; ioff += 16;
    int* row_r = ip + ioff; ioff += NN + 2;
    int* row_s = ip + ioff; ioff += NN + 2;
    int* zrow  = ip + ioff; ioff += 16;
    int* zlist = ip + ioff; ioff += NN;
    int2* cei    = (int2*)(ip + ioff); ioff += (size_t)EE * 2;
    int2* list_r = (int2*)(ip + ioff); ioff += (size_t)EE * 2;
    int2* list_s = (int2*)(ip + ioff); ioff += (size_t)EE * 2;
    unsigned short* wp = (unsigned short*)(ip + ioff);   // 28 pairs x 32768 shorts = 1.79 MB

    const int EG = (EE + 255) / 256;                // 625
    const int NG16 = (NN + 15) / 16;                // 626 (16 nodes/block)
    const int BNB  = ((NN + 63) / 64) * 2;          // 314
    const int BN3B = ((NN * 3 + 63) / 64) * 2;      // 938
    const int BS   = NE * 32;                       // 320
    const int ZB   = (out_size + 255) / 256;
    const int ZI   = (4 * NN + 48 + 255) / 256;
    tz_zero<<<ZB + ZI + 1600, 256, 0, stream>>>(out, out_size, deg_r, 4 * NN + 48, ZB, ZI,
                                                W_mix_s1, W_up2s, W_sk_s2, W_mix_s2, wp);
    tz_geomtab<<<683, 256, 0, stream>>>(positions, shifts, edge_index, ef, defdr, Y1, rr,
                                        cei, nact, deg_r, deg_s, node_z, zcnt,
                                        W_embed, W_up1, W_sk_s1, E1, T1, W_mix_v1, W_up2v, Wc,
                                        W_mix_s1, W_up2s, Wd);
    tz_scan<<<1, 1024, 0, stream>>>(deg_r, deg_s, zcnt, row_r, row_s, zrow);
    tz_fill3<<<5665 + 192, 256, 0, stream>>>(cei, nact, row_r, row_s, cur_r, cur_s,
                                             list_r, list_s, node_z, zcur, zrow, zlist,
                                             E1, T1, su1, s1, Wc, Wd, wp);
    tz_edge1<<<NG16, 256, 0, stream>>>(ef, Y1, R1, su1, row_r, list_r, A0, A1);
    tz_two<1, 0><<<BNB + BN3B, 256, 0, stream>>>(A0, wp + (size_t)0 * PAIR, s1, NN, INV_AVG,
                                                 A1, wp + (size_t)2 * PAIR, vup, NN * 3, INV_AVG, BNB);
    tz_mix<0, 0><<<BNB + BS, 256, 0, stream>>>(s1, wp + (size_t)4 * PAIR, s1u2, NN, 1.f,
                                               s1, wp + (size_t)5 * PAIR, s2, zrow, zlist, BNB);
    tz_edge2<<<NG16, 256, 0, stream>>>(ef, Y1, R2, s1u2, vup, row_r, list_r, A2);
    tz_one<1><<<BNB, 256, 0, stream>>>(A2, wp + (size_t)25 * PAIR, s2, NN, INV_AVG);
    tz_mlp<<<NN / 8, 256, 0, stream>>>(s2, W_mlp, w_out, w_r1, s1, g_s2, g_s1, e1n, e2n);
    tz_bwdmix<<<BNB + BS + 32, 256, 0, stream>>>(g_s2, wp + (size_t)26 * PAIR, A2,
                                                 wp + (size_t)15 * PAIR, g_s1,
                                                 zrow, zlist, node_z, batch, atomic_e,
                                                 e1n, e2n, out, BNB, BNB + BS);
    tz_bwdA<<<625 + NG16, 256, 0, stream>>>(ef, Y1, cei, nact, R2, A2, s1u2, vup,
                                            list_s, row_s, gefA, gyA, Gsj2, Gvj);
    tz_three<0, 0, 0><<<BN3B + BNB + BNB, 256, 0, stream>>>(
        Gvj, wp + (size_t)3 * PAIR, A1, NN * 3, INV_AVG,
        g_s1, wp + (size_t)1 * PAIR, A0, NN, INV_AVG,
        Gsj2, wp + (size_t)27 * PAIR, A0b, NN, INV_AVG, BN3B, BN3B + BNB);
    tz_bwdB<<<EG, 256, 0, stream>>>(ef, Y1, cei, nact, R1, su1, A0, A0b, A1, list_r,
                                    gefA, gyA, defdr, rr, out + GG + GG * 3);
}